// Round 3
// baseline (3188.350 us; speedup 1.0000x reference)
//
#include <hip/hip_runtime.h>
#include <cmath>

typedef unsigned short u16;
typedef short bf16x8 __attribute__((ext_vector_type(8)));
typedef float f32x4 __attribute__((ext_vector_type(4)));

#define S_N 1025
#define W_N 128
#define H_N 200
#define FH_N 800
#define KP 232
#define SGP 911
#define SGW 804      // wrec sG row stride (floats); 804%32=4 stagger, gates<800
#define MID 512
#define NT 56
#define PKT (NT * 7 * 512)
// conflict-free LDS B-fragment layout: per-kcc stride 544 u16, per-quadk 136
#define PKC 544
#define QKS 136
#define FRAGSZ (7 * PKC)   // 3808 u16 per array

__device__ __forceinline__ float bf2f(u16 u) {
  unsigned int x = ((unsigned int)u) << 16;
  return __builtin_bit_cast(float, x);
}
__device__ __forceinline__ u16 f2bf(float f) {
  unsigned int x = __builtin_bit_cast(unsigned int, f);
  x += 0x7fffu + ((x >> 16) & 1u);
  return (u16)(x >> 16);
}
#define LOG2E 1.44269504088896f
__device__ __forceinline__ float fsigm(float x) {
  float e = __builtin_amdgcn_exp2f(-fabsf(x) * LOG2E);
  float p = __builtin_amdgcn_rcpf(1.f + e);
  return x >= 0.f ? p : 1.f - p;
}
__device__ __forceinline__ float ftanh(float x) {
  float e = __builtin_amdgcn_exp2f(-2.f * fabsf(x) * LOG2E);
  float th = (1.f - e) * __builtin_amdgcn_rcpf(1.f + e);
  return x >= 0.f ? th : -th;
}

__device__ __forceinline__ const bf16x8* pkptr(const u16* pk, int tt, int kcc, int lane) {
  return (const bf16x8*)(pk + (size_t)((tt * 7 + kcc) * 512 + lane * 8));
}
// writer: element (row m 0..15, k 0..199) -> padded LDS fragment index
__device__ __forceinline__ int fidx(int m, int k) {
  return (k >> 5) * PKC + ((k >> 3) & 3) * QKS + m * 8 + (k & 7);
}
// reader: lane's 16B fragment for k-chunk kcc (16B-aligned: QKS*2=272=17*16)
__device__ __forceinline__ const bf16x8* frg(const u16* base, int kcc, int lane) {
  return (const bf16x8*)(base + kcc * PKC + (lane >> 4) * QKS + (lane & 15) * 8);
}

// AGPR-pinned MFMA (weights live in the accumulator half of the unified RF;
// the compiler never does this on its own — arch VGPRs cap at 256).
// Hazards are handled MANUALLY at the call site (asm is opaque to the GCN
// hazard recognizer): sched_barrier + s_nop block before any read of acc.
// "=&v" earlyclobber: MFMA D must not alias A/B. Inline-const 0 as C on the
// first K-slice avoids both the zero-movs and the VALU->MFMA srcC hazard.
#define MFMA_A_Z(acc, Aag, Bv)                                               \
  asm volatile("v_mfma_f32_16x16x32_bf16 %0, %1, %2, 0"                      \
      : "=&v"(acc) : "a"(Aag), "v"(Bv))
#define MFMA_A(acc, Aag, Bv)                                                 \
  asm volatile("v_mfma_f32_16x16x32_bf16 %0, %1, %2, %0"                     \
      : "+v"(acc) : "a"(Aag), "v"(Bv))

// ---------------------------------------------------------------------------
// Kernel 0: repack 8 fp32 weight matrices to bf16 MFMA fragment order.
// dst: [wih_ctx|whh_ctx|wih_tgt|whh_tgt|whh_prev|whh_post|wih_prev|wih_post]
// w==4/5 (whh_prev/whh_post, consumed only by k_sent) use GATE-INTERLEAVED
// rows: A-row16 = j_local*4 + gate, so each k_sent lane's f32x4 acc is the
// (i,f,g,o) gates of a single hidden unit.
// ---------------------------------------------------------------------------
__global__ __launch_bounds__(256) void k_w2b(
    const float* __restrict__ p0, const float* __restrict__ p1,
    const float* __restrict__ p2, const float* __restrict__ p3,
    const float* __restrict__ p4, const float* __restrict__ p5,
    const float* __restrict__ p6, const float* __restrict__ p7,
    u16* __restrict__ dst)
{
  int i = blockIdx.x * 256 + threadIdx.x;
  if (i >= 8 * PKT) return;
  int w = i / PKT, r = i - w * PKT;
  int tt = r / 3584;
  int q = r - tt * 3584;
  int kcc = q >> 9;
  int lane = (q >> 3) & 63;
  int j = q & 7;
  int col = lane & 15, quad = lane >> 4;
  int k = kcc * 32 + quad * 8 + j;
  const float* ps[8] = {p0, p1, p2, p3, p4, p5, p6, p7};
  u16 v = 0;
  if (w == 4 || w == 5) {
    int jj = tt * 4 + (col >> 2);     // hidden unit
    int gp = col & 3;                 // gate part i/f/g/o
    if (jj < H_N && k < H_N) v = f2bf(ps[w][((size_t)gp * H_N + jj) * H_N + k]);
  } else {
    int gate = tt * 16 + col;
    if (gate < FH_N && k < H_N) v = f2bf(ps[w][(size_t)gate * H_N + k]);
  }
  dst[i] = v;
}

// ---------------------------------------------------------------------------
// Kernel 0b: bitonic sort of sentence ids by length (desc) -> order[]
// ---------------------------------------------------------------------------
__global__ __launch_bounds__(1024) void k_sort(
    const int* __restrict__ lengths, int* __restrict__ order)
{
  __shared__ int key[2048], val[2048];
  int tid = threadIdx.x;
  for (int v = 0; v < 2; ++v) {
    int i = tid + v * 1024;
    key[i] = (i < S_N) ? lengths[i] : -1;
    val[i] = (i < S_N) ? i : (S_N - 1);
  }
  __syncthreads();
  for (int k = 2; k <= 2048; k <<= 1)
    for (int j = k >> 1; j > 0; j >>= 1) {
      for (int v = 0; v < 2; ++v) {
        int i = tid + v * 1024;
        int ix = i ^ j;
        if (ix > i) {
          bool descRegion = ((i & k) == 0);
          int ki = key[i], kx = key[ix];
          if ((ki < kx) == descRegion) {
            key[i] = kx; key[ix] = ki;
            int tv = val[i]; val[i] = val[ix]; val[ix] = tv;
          }
        }
      }
      __syncthreads();
    }
  for (int v = 0; v < 2; ++v) {
    int i = tid + v * 1024;
    if (i < S_N) order[i] = val[i];
  }
}

// ---------------------------------------------------------------------------
// Kernel X: chunked input-projection GEMM (conflict-free staging layout).
// gxc[slot][tc][gate] = words[s][c*CH+tc] @ wih^T + (bih+bhh).
// slot 0..1024 = ctx on sentence slot; slot 1025 = tgt on MID.
// ---------------------------------------------------------------------------
__global__ __launch_bounds__(512, 1) void k_xpack(
    int c, int CH,
    const float* __restrict__ words, const int* __restrict__ lengths,
    const u16* __restrict__ wihb_ctx, const float* __restrict__ bih_ctx, const float* __restrict__ bhh_ctx,
    const u16* __restrict__ wihb_tgt, const float* __restrict__ bih_tgt, const float* __restrict__ bhh_tgt,
    float* __restrict__ gxc)
{
  const int slot = blockIdx.x % 1026;
  const int tile = blockIdx.x / 1026;
  const int t0f = tile * 16;
  const bool tg = (slot == 1025);
  const int s = tg ? MID : slot;
  const int len = lengths[s];
  const int tbase = c * CH + t0f;
  if (t0f >= CH || tbase >= len) return;
  const u16* wih = tg ? wihb_tgt : wihb_ctx;
  const float* bih = tg ? bih_tgt : bih_ctx;
  const float* bhh = tg ? bhh_tgt : bhh_ctx;

  __shared__ __align__(16) u16 sXh[FRAGSZ];
  __shared__ __align__(16) u16 sXl[FRAGSZ];
  __shared__ float sBias[FH_N];
  const int tid = threadIdx.x;
  for (int e = tid; e < FRAGSZ; e += 512) { sXh[e] = 0; sXl[e] = 0; }
  for (int e = tid; e < FH_N; e += 512) sBias[e] = bih[e] + bhh[e];
  __syncthreads();
  const int nrow = min(16, min(CH - t0f, len - tbase));
  for (int e = tid; e < nrow * H_N; e += 512) {
    int tr = e / H_N, k = e - tr * H_N;
    float v = words[((size_t)s * W_N + tbase + tr) * H_N + k];
    u16 vh = f2bf(v);
    int idx = fidx(tr, k);
    sXh[idx] = vh;
    sXl[idx] = f2bf(v - bf2f(vh));
  }
  __syncthreads();

  const int lane = tid & 63, wv = tid >> 6, quad = lane >> 4, col = lane & 15;
  const int tcg = t0f + col;
  const bool okcol = (tcg < CH) && (c * CH + tcg < len);

#pragma unroll
  for (int i = 0; i < 7; ++i) {
    int tt = wv + 8 * i;
    if (tt < 50) {                      // wave-uniform: skip pad tiles
      f32x4 acc = {0.f, 0.f, 0.f, 0.f};
#pragma unroll
      for (int kcc = 0; kcc < 7; ++kcc) {
        bf16x8 Aw = *pkptr(wih, tt, kcc, lane);
        bf16x8 bxh = *frg(sXh, kcc, lane);
        bf16x8 bxl = *frg(sXl, kcc, lane);
        acc = __builtin_amdgcn_mfma_f32_16x16x32_bf16(Aw, bxh, acc, 0, 0, 0);
        acc = __builtin_amdgcn_mfma_f32_16x16x32_bf16(Aw, bxl, acc, 0, 0, 0);
      }
      if (okcol) {
        float b0 = sBias[tt * 16 + quad * 4 + 0];
        float b1 = sBias[tt * 16 + quad * 4 + 1];
        float b2 = sBias[tt * 16 + quad * 4 + 2];
        float b3 = sBias[tt * 16 + quad * 4 + 3];
        f32x4 o = {acc[0] + b0, acc[1] + b1, acc[2] + b2, acc[3] + b3};
        *(f32x4*)(gxc + ((size_t)slot * CH + tcg) * FH_N + tt * 16 + quad * 4) = o;
      }
    }
  }
}

// ---------------------------------------------------------------------------
// Kernel R: chunked word-level recurrence. whh register/AGPR-resident
// afr[7][7]; B = 16 sentences' h (hi/lo) in the conflict-free frag layout.
// gx loads issued after acc->sG (acc regs freed), consumed post-barrier.
// ---------------------------------------------------------------------------
__global__ __launch_bounds__(512, 1) void k_wrec(
    int c, int CH,
    const int* __restrict__ lengths, const int* __restrict__ order,
    const float* __restrict__ h0w, const float* __restrict__ c0w,
    const u16* __restrict__ whhb_ctx, const u16* __restrict__ whhb_tgt,
    const float* __restrict__ gxc,
    float* __restrict__ stateH, float* __restrict__ stateC,
    float* __restrict__ emb)
{
  const int tid = threadIdx.x;
  const int b = blockIdx.x;
  const bool is_tgt = (b == 65);
  const u16* whh = is_tgt ? whhb_tgt : whhb_ctx;

  __shared__ __align__(16) u16 sBh[FRAGSZ];
  __shared__ __align__(16) u16 sBl[FRAGSZ];
  __shared__ float sG[16 * SGW];
  __shared__ int sLen[16], sId[16];

  if (tid < 16) {
    int slot = b * 16 + tid;
    int s = is_tgt ? MID : order[min(slot, S_N - 1)];
    sId[tid] = s;
    sLen[tid] = lengths[s];
  }
  __syncthreads();
  int Lmax = 1;
  for (int m = 0; m < 16; ++m) Lmax = max(Lmax, sLen[m]);
  if (c * CH >= Lmax) return;

  const int lane = tid & 63;
  const int wv = tid >> 6;
  const int quad = lane >> 4;
  const int col = lane & 15;

  bf16x8 afr[7][7];
#pragma unroll
  for (int i = 0; i < 7; ++i)
#pragma unroll
    for (int kcc = 0; kcc < 7; ++kcc)
      afr[i][kcc] = *pkptr(whh, wv + 8 * i, kcc, lane);

  for (int e = tid; e < FRAGSZ; e += 512) { sBh[e] = 0; sBl[e] = 0; }
  __syncthreads();

  float creg[7];
#pragma unroll
  for (int rr = 0; rr < 7; ++rr) {
    int e = tid + 512 * rr;
    if (e < 16 * H_N) {
      int m = e / H_N, j = e - m * H_N;
      float h, cc;
      if (c == 0) {
        int s = sId[m];
        h = h0w[(size_t)s * H_N + j];
        cc = c0w[(size_t)s * H_N + j];
      } else {
        h = stateH[(size_t)(b * 16 + m) * H_N + j];
        cc = stateC[(size_t)(b * 16 + m) * H_N + j];
      }
      creg[rr] = cc;
      u16 hh = f2bf(h);
      int idx = fidx(m, j);
      sBh[idx] = hh;
      sBl[idx] = f2bf(h - bf2f(hh));
    }
  }
  __syncthreads();

#pragma unroll 1
  for (int tc = 0; tc < CH; ++tc) {
    const int t = c * CH + tc;
    if (t >= Lmax) break;

    f32x4 acc[7];
#pragma unroll
    for (int i = 0; i < 7; ++i) { f32x4 z = {0.f, 0.f, 0.f, 0.f}; acc[i] = z; }
#pragma unroll
    for (int kcc = 0; kcc < 7; ++kcc) {
      bf16x8 bh = *frg(sBh, kcc, lane);
      bf16x8 bl = *frg(sBl, kcc, lane);
#pragma unroll
      for (int i = 0; i < 7; ++i) {
        if (wv + 8 * i < 50) {          // wave-uniform: skip pad tiles
          acc[i] = __builtin_amdgcn_mfma_f32_16x16x32_bf16(afr[i][kcc], bh, acc[i], 0, 0, 0);
          acc[i] = __builtin_amdgcn_mfma_f32_16x16x32_bf16(afr[i][kcc], bl, acc[i], 0, 0, 0);
        }
      }
    }
#pragma unroll
    for (int i = 0; i < 7; ++i) {
      int tt = wv + 8 * i;
      if (tt < 50)
        *(f32x4*)(sG + col * SGW + tt * 16 + quad * 4) = acc[i];
    }

    // issue gx loads now (acc freed); latency overlaps the barrier drain
    float gv[7][4];
#pragma unroll
    for (int rr = 0; rr < 7; ++rr) {
      int e = tid + 512 * rr;
      if (e < 16 * H_N) {
        int m = e / H_N, j = e - m * H_N;
        int gslot = is_tgt ? 1025 : sId[m];
        const float* gp = gxc + ((size_t)gslot * CH + tc) * FH_N + j;
        gv[rr][0] = gp[0];
        gv[rr][1] = gp[H_N];
        gv[rr][2] = gp[2 * H_N];
        gv[rr][3] = gp[3 * H_N];
      }
    }
    __syncthreads();

#pragma unroll
    for (int rr = 0; rr < 7; ++rr) {
      int e = tid + 512 * rr;
      if (e < 16 * H_N) {
        int m = e / H_N, j = e - m * H_N;
        const float* gRow = sG + m * SGW + j;
        float ig = gRow[0] + gv[rr][0];
        float fg = gRow[H_N] + gv[rr][1];
        float gg = gRow[2 * H_N] + gv[rr][2];
        float og = gRow[3 * H_N] + gv[rr][3];
        float nc = fsigm(fg) * creg[rr] + fsigm(ig) * ftanh(gg);
        float nh = fsigm(og) * ftanh(nc);
        creg[rr] = nc;
        u16 hh = f2bf(nh);
        int idx = fidx(m, j);
        sBh[idx] = hh;
        sBl[idx] = f2bf(nh - bf2f(hh));
        if (t == sLen[m] - 1) {
          int s = sId[m];
          if (is_tgt) {
            if (m == 0) emb[(size_t)MID * H_N + j] = nh;
          } else if (s != MID) {
            emb[(size_t)s * H_N + j] = nh;
          }
        }
      }
    }
    __syncthreads();
  }

#pragma unroll
  for (int rr = 0; rr < 7; ++rr) {
    int e = tid + 512 * rr;
    if (e < 16 * H_N) {
      int m = e / H_N, j = e - m * H_N;
      int idx = fidx(m, j);
      stateH[(size_t)(b * 16 + m) * H_N + j] = bf2f(sBh[idx]) + bf2f(sBl[idx]);
      stateC[(size_t)(b * 16 + m) * H_N + j] = creg[rr];
    }
  }
}

// ---------------------------------------------------------------------------
// Fallback (tiny ws): streaming word kernel (round-5 style, unchanged).
// ---------------------------------------------------------------------------
__global__ __launch_bounds__(512, 1) void k_word_s(
    const float* __restrict__ words, const int* __restrict__ lengths,
    const int* __restrict__ order,
    const float* __restrict__ h0w, const float* __restrict__ c0w,
    const u16* __restrict__ wihb_ctx, const u16* __restrict__ whhb_ctx,
    const float* __restrict__ bih_ctx, const float* __restrict__ bhh_ctx,
    const u16* __restrict__ wihb_tgt, const u16* __restrict__ whhb_tgt,
    const float* __restrict__ bih_tgt, const float* __restrict__ bhh_tgt,
    float* __restrict__ emb)
{
  const int tid = threadIdx.x;
  const int b = blockIdx.x;
  const bool is_tgt = (b == 65);
  const u16* wih = is_tgt ? wihb_tgt : wihb_ctx;
  const u16* whh = is_tgt ? whhb_tgt : whhb_ctx;
  const float* bih = is_tgt ? bih_tgt : bih_ctx;
  const float* bhh = is_tgt ? bhh_tgt : bhh_ctx;

  __shared__ __align__(16) u16 sXhi[16 * KP];
  __shared__ __align__(16) u16 sXlo[16 * KP];
  __shared__ __align__(16) u16 sHi[16 * KP];
  __shared__ __align__(16) u16 sLo[16 * KP];
  __shared__ float sG[8 * SGP];
  __shared__ float sB[4 * H_N];
  __shared__ int sLen[16], sId[16];

  for (int e = tid; e < 16 * KP; e += 512) {
    sXhi[e] = 0; sXlo[e] = 0; sHi[e] = 0; sLo[e] = 0;
  }
  if (tid < 16) {
    int slot = b * 16 + tid;
    int s = is_tgt ? MID : order[min(slot, S_N - 1)];
    sId[tid] = s;
    sLen[tid] = lengths[s];
  }
  for (int e = tid; e < 4 * H_N; e += 512) sB[e] = bih[e] + bhh[e];
  __syncthreads();

  float creg[7];
#pragma unroll
  for (int r = 0; r < 7; ++r) {
    int e = tid + 512 * r;
    if (e < 16 * H_N) {
      int m = e / H_N, j = e - m * H_N;
      int s = sId[m];
      float h = h0w[(size_t)s * H_N + j];
      u16 hh = f2bf(h);
      sHi[m * KP + j] = hh;
      sLo[m * KP + j] = f2bf(h - bf2f(hh));
      creg[r] = c0w[(size_t)s * H_N + j];
    }
  }
  __syncthreads();
  int Lmax = 1;
  for (int m = 0; m < 16; ++m) Lmax = max(Lmax, sLen[m]);

  const int lane = tid & 63;
  const int wv = tid >> 6;
  const int quad = lane >> 4;
  const int col = lane & 15;
  const int hpass = quad >> 1;

  const u16* aXh = sXhi + col * KP + quad * 8;
  const u16* aXl = sXlo + col * KP + quad * 8;
  const u16* aHh = sHi  + col * KP + quad * 8;
  const u16* aHl = sLo  + col * KP + quad * 8;

#pragma unroll 1
  for (int t = 0; t < Lmax; ++t) {
    for (int e = tid; e < 16 * H_N; e += 512) {
      int m = e / H_N, k = e - m * H_N;
      float v = words[((size_t)sId[m] * W_N + t) * H_N + k];
      u16 vh = f2bf(v);
      sXhi[m * KP + k] = vh;
      sXlo[m * KP + k] = f2bf(v - bf2f(vh));
    }
    __syncthreads();

    f32x4 acc[7];
#pragma unroll
    for (int i = 0; i < 7; ++i) { f32x4 z4 = {0.f, 0.f, 0.f, 0.f}; acc[i] = z4; }

#pragma unroll
    for (int kcc = 0; kcc < 7; ++kcc) {
      bf16x8 axh = *(const bf16x8*)(aXh + kcc * 32);
      bf16x8 axl = *(const bf16x8*)(aXl + kcc * 32);
      bf16x8 ahh = *(const bf16x8*)(aHh + kcc * 32);
      bf16x8 ahl = *(const bf16x8*)(aHl + kcc * 32);
#pragma unroll
      for (int i = 0; i < 7; ++i) {
        if (wv + 8 * i < 50) {
          bf16x8 bw = *pkptr(wih, wv + 8 * i, kcc, lane);
          bf16x8 bh = *pkptr(whh, wv + 8 * i, kcc, lane);
          acc[i] = __builtin_amdgcn_mfma_f32_16x16x32_bf16(axh, bw, acc[i], 0, 0, 0);
          acc[i] = __builtin_amdgcn_mfma_f32_16x16x32_bf16(axl, bw, acc[i], 0, 0, 0);
          acc[i] = __builtin_amdgcn_mfma_f32_16x16x32_bf16(ahh, bh, acc[i], 0, 0, 0);
          acc[i] = __builtin_amdgcn_mfma_f32_16x16x32_bf16(ahl, bh, acc[i], 0, 0, 0);
        }
      }
    }

#pragma unroll 1
    for (int h = 0; h < 2; ++h) {
      if (hpass == h) {
#pragma unroll
        for (int i = 0; i < 7; ++i) {
          int tt = wv + 8 * i;
          if (tt < 50) {
#pragma unroll
            for (int r = 0; r < 4; ++r)
              sG[((quad & 1) * 4 + r) * SGP + tt * 16 + col] = acc[i][r];
          }
        }
      }
      __syncthreads();
#pragma unroll
      for (int rr = 0; rr < 7; ++rr) {
        int e = tid + 512 * rr;
        if (e < 16 * H_N) {
          int m = e / H_N, j = e - m * H_N;
          if ((m >> 3) == h) {
            const float* gRow = sG + (m - 8 * h) * SGP;
            float ig = gRow[j] + sB[j];
            float fg = gRow[H_N + j] + sB[H_N + j];
            float gg = gRow[2 * H_N + j] + sB[2 * H_N + j];
            float og = gRow[3 * H_N + j] + sB[3 * H_N + j];
            float nc = fsigm(fg) * creg[rr] + fsigm(ig) * ftanh(gg);
            float nh = fsigm(og) * ftanh(nc);
            creg[rr] = nc;
            u16 hh = f2bf(nh);
            sHi[m * KP + j] = hh;
            sLo[m * KP + j] = f2bf(nh - bf2f(hh));
            if (t == sLen[m] - 1) {
              int s = sId[m];
              if (is_tgt) {
                if (m == 0) emb[(size_t)MID * H_N + j] = nh;
              } else if (s != MID) {
                emb[(size_t)s * H_N + j] = nh;
              }
            }
          }
        }
      }
      __syncthreads();
    }
  }
}

// ---------------------------------------------------------------------------
// Kernel 2: gx projections for prev/post via MFMA (packed wih).
// Output layout INTERLEAVED for k_sent: gx[t][j*4 + gate], gate 0..3=i,f,g,o.
// ---------------------------------------------------------------------------
__global__ __launch_bounds__(512) void k_gx(
    const float* __restrict__ emb,
    const u16* __restrict__ wihb_prev, const float* __restrict__ bih_prev, const float* __restrict__ bhh_prev,
    const u16* __restrict__ wihb_post, const float* __restrict__ bih_post, const float* __restrict__ bhh_post,
    float* __restrict__ gxp, float* __restrict__ gxq)
{
  const int tid = threadIdx.x;
  const int b = blockIdx.x;
  const bool post = (b >= 33);
  const int t0 = (post ? b - 33 : b) * 16;
  const u16* wih = post ? wihb_post : wihb_prev;
  const float* bih = post ? bih_post : bih_prev;
  const float* bhh = post ? bhh_post : bhh_prev;
  float* out = post ? gxq : gxp;

  __shared__ __align__(16) u16 sEhi[16 * KP];
  __shared__ __align__(16) u16 sElo[16 * KP];
  for (int e = tid; e < 16 * KP; e += 512) { sEhi[e] = 0; sElo[e] = 0; }
  __syncthreads();
  for (int e = tid; e < 16 * H_N; e += 512) {
    int m = e / H_N, k = e - m * H_N;
    int t = t0 + m;
    if (t <= 512) {
      int src = post ? (1024 - t) : t;
      float v = emb[(size_t)src * H_N + k];
      u16 vh = f2bf(v);
      sEhi[m * KP + k] = vh;
      sElo[m * KP + k] = f2bf(v - bf2f(vh));
    }
  }
  __syncthreads();

  const int lane = tid & 63;
  const int wv = tid >> 6;
  const int quad = lane >> 4;
  const int col = lane & 15;
  const u16* aH = sEhi + col * KP + quad * 8;
  const u16* aL = sElo + col * KP + quad * 8;

#pragma unroll 1
  for (int i = 0; i < 7; ++i) {
    int tt = wv + 8 * i;
    if (tt >= 50) break;
    int gate = tt * 16 + col;
    f32x4 acc = {0.f, 0.f, 0.f, 0.f};
#pragma unroll
    for (int kcc = 0; kcc < 7; ++kcc) {
      bf16x8 Ah = *(const bf16x8*)(aH + kcc * 32);
      bf16x8 Al = *(const bf16x8*)(aL + kcc * 32);
      bf16x8 bw = *pkptr(wih, tt, kcc, lane);
      acc = __builtin_amdgcn_mfma_f32_16x16x32_bf16(Ah, bw, acc, 0, 0, 0);
      acc = __builtin_amdgcn_mfma_f32_16x16x32_bf16(Al, bw, acc, 0, 0, 0);
    }
    float bias = bih[gate] + bhh[gate];
    int gp = gate >= 600 ? 3 : (gate >= 400 ? 2 : (gate >= 200 ? 1 : 0));
    int jg = gate - gp * 200;
#pragma unroll
    for (int r = 0; r < 4; ++r) {
      int t = t0 + quad * 4 + r;
      if (t <= 512) out[(size_t)t * FH_N + jg * 4 + gp] = acc[r] + bias;
    }
  }
}

// ---------------------------------------------------------------------------
// Kernel 3: prev/post sentence LSTMs, 513 serial steps.
// 256 threads, 1 wave/SIMD (512-reg unified budget). Weights split across
// the register file: 63 fragments -> AGPR (252 <= 256 arch cap) via asm "a"
// constraint; 28 fragments -> VGPR (112 regs) via builtin MFMA. Round-2
// lesson: the AGPR file caps at 256 regs, and asm MFMAs are invisible to
// the hazard recognizer -> manual s_nop block (pinned by sched_barrier)
// between the MFMA cluster and the acc reads, earlyclobber on zero-C form.
// Gate-interleaved whh packing: each lane's f32x4 acc = (i,f,g,o) of hidden
// unit j = tt*4+quad; hi/lo via B-column trick (cols 0-7 hi, 8-15 lo).
// ---------------------------------------------------------------------------
__global__ __launch_bounds__(256, 1) void k_sent(
    const u16* __restrict__ whhb_prev, const u16* __restrict__ whhb_post,
    const float* __restrict__ h0p, const float* __restrict__ c0p,
    const float* __restrict__ h0q, const float* __restrict__ c0q,
    const float* __restrict__ gxp, const float* __restrict__ gxq,
    float* __restrict__ outp, float* __restrict__ outq)
{
  const int tid = threadIdx.x;
  const bool post = (blockIdx.x != 0);
  const u16* whh = post ? whhb_post : whhb_prev;
  const float* h0 = post ? h0q : h0p;
  const float* c0 = post ? c0q : c0p;
  const float* gx = post ? gxq : gxp;
  float* outv = post ? outq : outp;

  __shared__ __align__(16) u16 sHi[224];
  __shared__ __align__(16) u16 sLo[224];
  __shared__ __align__(16) float sGt[H_N * 8];   // [j][0..3]=hi, [j][4..7]=lo

  const int lane = tid & 63;
  const int wv = tid >> 6;
  const int quad = lane >> 4;
  const int col = lane & 15;

  // wave wv owns tiles tt = wv + 4*i, i=0..12 (pad tiles tt>=50 are zeros).
  // i=0..8 -> AGPR-resident (asm), i=9..12 -> VGPR-resident (builtin).
  bf16x8 afrA[9][7];
  bf16x8 afrV[4][7];
#pragma unroll
  for (int i = 0; i < 9; ++i)
#pragma unroll
    for (int kcc = 0; kcc < 7; ++kcc)
      afrA[i][kcc] = *pkptr(whh, wv + 4 * i, kcc, lane);
#pragma unroll
  for (int iv = 0; iv < 4; ++iv)
#pragma unroll
    for (int kcc = 0; kcc < 7; ++kcc)
      afrV[iv][kcc] = *pkptr(whh, wv + 4 * (9 + iv), kcc, lane);

  if (tid < 224) { sHi[tid] = 0; sLo[tid] = 0; }
  float c = 0.f, last_h = 0.f;
  if (tid < H_N) {
    float h = h0[tid];
    u16 hh = f2bf(h);
    sHi[tid] = hh;
    sLo[tid] = f2bf(h - bf2f(hh));
    c = c0[tid];
  }
  __syncthreads();

  const u16* hb = ((lane & 8) ? sLo : sHi) + quad * 8;
  const bool wr = ((col & 7) == 0);   // cols 0 (hi) and 8 (lo) write gates
  const int wroff = (col >> 1);       // 0 or 4 floats

  f32x4 gc = {0.f, 0.f, 0.f, 0.f};
  if (tid < H_N) gc = *(const f32x4*)(gx + (size_t)tid * 4);

#pragma unroll 1
  for (int t = 0; t < 513; ++t) {
    bf16x8 bfr[7];
#pragma unroll
    for (int kcc = 0; kcc < 7; ++kcc) bfr[kcc] = *(const bf16x8*)(hb + kcc * 32);

    // prefetch next step's gx; HBM/L2 latency hides under the MFMA phase
    f32x4 gn = {0.f, 0.f, 0.f, 0.f};
    if (t + 1 < 513 && tid < H_N)
      gn = *(const f32x4*)(gx + (size_t)(t + 1) * FH_N + tid * 4);

    // VGPR-weight tiles: builtin MFMA (compiler-managed hazards)
    f32x4 accV[4];
#pragma unroll
    for (int iv = 0; iv < 4; ++iv) { f32x4 z = {0.f, 0.f, 0.f, 0.f}; accV[iv] = z; }
#pragma unroll
    for (int kcc = 0; kcc < 7; ++kcc)
#pragma unroll
      for (int iv = 0; iv < 4; ++iv)
        if (wv + 4 * (9 + iv) < 50)     // wave-uniform pad-tile skip
          accV[iv] = __builtin_amdgcn_mfma_f32_16x16x32_bf16(
              afrV[iv][kcc], bfr[kcc], accV[iv], 0, 0, 0);

    // AGPR-weight tiles: asm MFMA, zero-C first slice, accumulate after
    f32x4 acc[9];
#pragma unroll
    for (int i = 0; i < 9; ++i) MFMA_A_Z(acc[i], afrA[i][0], bfr[0]);
#pragma unroll
    for (int kcc = 1; kcc < 7; ++kcc)
#pragma unroll
      for (int i = 0; i < 9; ++i)
        MFMA_A(acc[i], afrA[i][kcc], bfr[kcc]);

    // manual hazard drain: asm MFMAs are invisible to the hazard recognizer;
    // sched_barrier pins the nops between the MFMA cluster and the reads.
    __builtin_amdgcn_sched_barrier(0);
    asm volatile("s_nop 7\n\ts_nop 7\n\ts_nop 7" ::);
    __builtin_amdgcn_sched_barrier(0);

    if (wr) {
#pragma unroll
      for (int i = 0; i < 9; ++i) {
        int tt = wv + 4 * i;
        *(f32x4*)(sGt + (tt * 4 + quad) * 8 + wroff) = acc[i];
      }
#pragma unroll
      for (int iv = 0; iv < 4; ++iv) {
        int tt = wv + 4 * (9 + iv);
        if (tt < 50)
          *(f32x4*)(sGt + (tt * 4 + quad) * 8 + wroff) = accV[iv];
      }
    }
    __syncthreads();

    if (tid < H_N) {
      f32x4 ga = *(const f32x4*)(sGt + tid * 8);
      f32x4 gb = *(const f32x4*)(sGt + tid * 8 + 4);
      float ig = ga[0] + gb[0] + gc[0];
      float fg = ga[1] + gb[1] + gc[1];
      float gg = ga[2] + gb[2] + gc[2];
      float og = ga[3] + gb[3] + gc[3];
      float nc = fsigm(fg) * c + fsigm(ig) * ftanh(gg);
      float nh = fsigm(og) * ftanh(nc);
      c = nc;
      last_h = nh;
      u16 hh = f2bf(nh);
      sHi[tid] = hh;
      sLo[tid] = f2bf(nh - bf2f(hh));
    }
    gc = gn;
    __syncthreads();
  }
  if (tid < H_N) outv[tid] = last_h;
}

// ---------------------------------------------------------------------------
// Kernel 4: out = [prev_out ; post_out] @ fc_w^T + fc_b
// ---------------------------------------------------------------------------
__global__ __launch_bounds__(256) void k_fc(
    const float* __restrict__ pout, const float* __restrict__ qout,
    const float* __restrict__ fc_w, const float* __restrict__ fc_b,
    float* __restrict__ out)
{
  const int tid = threadIdx.x;
  if (tid < H_N) {
    float d = fc_b[tid];
    const float* wr = fc_w + (size_t)tid * 2 * H_N;
    for (int k = 0; k < H_N; ++k) d += pout[k] * wr[k];
    for (int k = 0; k < H_N; ++k) d += qout[k] * wr[H_N + k];
    out[tid] = d;
  }
}

extern "C" void kernel_launch(void* const* d_in, const int* in_sizes, int n_in,
                              void* d_out, int out_size, void* d_ws, size_t ws_size,
                              hipStream_t stream) {
  const float* words   = (const float*)d_in[0];
  const int*   lengths = (const int*)d_in[1];
  const float* h0w = (const float*)d_in[2];
  const float* c0w = (const float*)d_in[3];
  const float* h0p = (const float*)d_in[4];
  const float* c0p = (const float*)d_in[5];
  const float* h0q = (const float*)d_in[6];
  const float* c0q = (const float*)d_in[7];
  const float* wih_ctx = (const float*)d_in[8];
  const float* whh_ctx = (const float*)d_in[9];
  const float* bih_ctx = (const float*)d_in[10];
  const float* bhh_ctx = (const float*)d_in[11];
  const float* wih_tgt = (const float*)d_in[12];
  const float* whh_tgt = (const float*)d_in[13];
  const float* bih_tgt = (const float*)d_in[14];
  const float* bhh_tgt = (const float*)d_in[15];
  const float* wih_prev = (const float*)d_in[16];
  const float* whh_prev = (const float*)d_in[17];
  const float* bih_prev = (const float*)d_in[18];
  const float* bhh_prev = (const float*)d_in[19];
  const float* wih_post = (const float*)d_in[20];
  const float* whh_post = (const float*)d_in[21];
  const float* bih_post = (const float*)d_in[22];
  const float* bhh_post = (const float*)d_in[23];
  const float* fc_w = (const float*)d_in[24];
  const float* fc_b = (const float*)d_in[25];
  (void)in_sizes; (void)n_in; (void)out_size;

  const size_t FIXF = 1448600;
  int CH = 0;
  for (int cand = 32; cand >= 1; cand >>= 1) {
    size_t needB = ((size_t)1026 * cand * 800 + FIXF) * 4 + 1056 * 4 + (size_t)8 * PKT * 2 + 256;
    if (ws_size >= needB) { CH = cand; break; }
  }

  float* ws = (float*)d_ws;
  float *gxc, *stateH, *stateC, *emb, *gxp, *gxq, *po, *qo;
  int* order;
  u16* wb;
  if (CH > 0) {
    gxc = ws;
    stateH = gxc + (size_t)1026 * CH * 800;
    stateC = stateH + 211200;
    emb = stateC + 211200;
    gxp = emb + 205000;
    gxq = gxp + 410400;
    po = gxq + 410400;
    qo = po + 200;
    order = (int*)(qo + 200);
    wb = (u16*)(order + 1056);
  } else {
    gxc = nullptr; stateH = nullptr; stateC = nullptr;
    emb = ws;
    gxp = ws + 205000;
    gxq = ws + 615400;
    po = ws + 1025800;
    qo = ws + 1026000;
    order = (int*)(ws + 1026200);
    wb = (u16*)(ws + 1027232);
  }
  u16* wihb_ctx  = wb;
  u16* whhb_ctx  = wb + PKT;
  u16* wihb_tgt  = wb + 2 * PKT;
  u16* whhb_tgt  = wb + 3 * PKT;
  u16* whhb_prev = wb + 4 * PKT;
  u16* whhb_post = wb + 5 * PKT;
  u16* wihb_prev = wb + 6 * PKT;
  u16* wihb_post = wb + 7 * PKT;

  k_w2b<<<(8 * PKT + 255) / 256, 256, 0, stream>>>(
      wih_ctx, whh_ctx, wih_tgt, whh_tgt, whh_prev, whh_post,
      wih_prev, wih_post, wb);
  k_sort<<<1, 1024, 0, stream>>>(lengths, order);

  if (CH > 0) {
    const int TT = (CH + 15) / 16;
    const int NC = (W_N + CH - 1) / CH;
    for (int c = 0; c < NC; ++c) {
      k_xpack<<<1026 * TT, 512, 0, stream>>>(c, CH, words, lengths,
                                             wihb_ctx, bih_ctx, bhh_ctx,
                                             wihb_tgt, bih_tgt, bhh_tgt, gxc);
      k_wrec<<<66, 512, 0, stream>>>(c, CH, lengths, order, h0w, c0w,
                                     whhb_ctx, whhb_tgt, gxc, stateH, stateC, emb);
    }
  } else {
    k_word_s<<<66, 512, 0, stream>>>(words, lengths, order, h0w, c0w,
                                     wihb_ctx, whhb_ctx, bih_ctx, bhh_ctx,
                                     wihb_tgt, whhb_tgt, bih_tgt, bhh_tgt, emb);
  }
  k_gx<<<66, 512, 0, stream>>>(emb, wihb_prev, bih_prev, bhh_prev,
                               wihb_post, bih_post, bhh_post, gxp, gxq);
  k_sent<<<2, 256, 0, stream>>>(whhb_prev, whhb_post, h0p, c0p, h0q, c0q,
                                gxp, gxq, po, qo);
  k_fc<<<1, 256, 0, stream>>>(po, qo, fc_w, fc_b, (float*)d_out);
}

// Round 5
// 2108.401 us; speedup vs baseline: 1.5122x; 1.5122x over previous
//
#include <hip/hip_runtime.h>
#include <cmath>

typedef unsigned short u16;
typedef short bf16x8 __attribute__((ext_vector_type(8)));
typedef float f32x4 __attribute__((ext_vector_type(4)));

#define S_N 1025
#define W_N 128
#define H_N 200
#define FH_N 800
#define KP 232
#define SGP 911
#define SGW 804      // wrec sG row stride (floats); 804%32=4 stagger, gates<800
#define MID 512
#define NT 56
#define PKT (NT * 7 * 512)
// conflict-free LDS B-fragment layout: per-kcc stride 544 u16, per-quadk 136
#define PKC 544
#define QKS 136
#define FRAGSZ (7 * PKC)   // 3808 u16 per array

__device__ __forceinline__ float bf2f(u16 u) {
  unsigned int x = ((unsigned int)u) << 16;
  return __builtin_bit_cast(float, x);
}
__device__ __forceinline__ u16 f2bf(float f) {
  unsigned int x = __builtin_bit_cast(unsigned int, f);
  x += 0x7fffu + ((x >> 16) & 1u);
  return (u16)(x >> 16);
}
#define LOG2E 1.44269504088896f
__device__ __forceinline__ float fsigm(float x) {
  float e = __builtin_amdgcn_exp2f(-fabsf(x) * LOG2E);
  float p = __builtin_amdgcn_rcpf(1.f + e);
  return x >= 0.f ? p : 1.f - p;
}
__device__ __forceinline__ float ftanh(float x) {
  float e = __builtin_amdgcn_exp2f(-2.f * fabsf(x) * LOG2E);
  float th = (1.f - e) * __builtin_amdgcn_rcpf(1.f + e);
  return x >= 0.f ? th : -th;
}

__device__ __forceinline__ const bf16x8* pkptr(const u16* pk, int tt, int kcc, int lane) {
  return (const bf16x8*)(pk + (size_t)((tt * 7 + kcc) * 512 + lane * 8));
}
// writer: element (row m 0..15, k 0..199) -> padded LDS fragment index
__device__ __forceinline__ int fidx(int m, int k) {
  return (k >> 5) * PKC + ((k >> 3) & 3) * QKS + m * 8 + (k & 7);
}
// reader: lane's 16B fragment for k-chunk kcc (16B-aligned: QKS*2=272=17*16)
__device__ __forceinline__ const bf16x8* frg(const u16* base, int kcc, int lane) {
  return (const bf16x8*)(base + kcc * PKC + (lane >> 4) * QKS + (lane & 15) * 8);
}

// AGPR-pinned MFMA. Round-4 lesson: keep total AGPR demand (asm weights +
// whatever the RA adds, e.g. builtin accs) <= 256 WITH SLACK — 252 asm AGPRs
// left no room and the RA's mid-loop AGPR tuple spills around opaque asm
// produced wrong results. This round: 224 asm AGPRs (8 tiles/wave), 32 slack.
// Hazards handled manually: asm cluster runs first; the builtin-LDS cluster
// (~300 cyc) plus sched_barrier + 6x s_nop 7 separate asm writes from reads.
#define MFMA_A_Z(acc, Aag, Bv)                                               \
  asm volatile("v_mfma_f32_16x16x32_bf16 %0, %1, %2, 0"                      \
      : "=&v"(acc) : "a"(Aag), "v"(Bv))
#define MFMA_A(acc, Aag, Bv)                                                 \
  asm volatile("v_mfma_f32_16x16x32_bf16 %0, %1, %2, %0"                     \
      : "+v"(acc) : "a"(Aag), "v"(Bv))

// ---------------------------------------------------------------------------
// Kernel 0: repack 8 fp32 weight matrices to bf16 MFMA fragment order.
// dst: [wih_ctx|whh_ctx|wih_tgt|whh_tgt|whh_prev|whh_post|wih_prev|wih_post]
// w==4/5 (whh_prev/whh_post, consumed only by k_sent) use GATE-INTERLEAVED
// rows: A-row16 = j_local*4 + gate, so each k_sent lane's f32x4 acc is the
// (i,f,g,o) gates of a single hidden unit.
// ---------------------------------------------------------------------------
__global__ __launch_bounds__(256) void k_w2b(
    const float* __restrict__ p0, const float* __restrict__ p1,
    const float* __restrict__ p2, const float* __restrict__ p3,
    const float* __restrict__ p4, const float* __restrict__ p5,
    const float* __restrict__ p6, const float* __restrict__ p7,
    u16* __restrict__ dst)
{
  int i = blockIdx.x * 256 + threadIdx.x;
  if (i >= 8 * PKT) return;
  int w = i / PKT, r = i - w * PKT;
  int tt = r / 3584;
  int q = r - tt * 3584;
  int kcc = q >> 9;
  int lane = (q >> 3) & 63;
  int j = q & 7;
  int col = lane & 15, quad = lane >> 4;
  int k = kcc * 32 + quad * 8 + j;
  const float* ps[8] = {p0, p1, p2, p3, p4, p5, p6, p7};
  u16 v = 0;
  if (w == 4 || w == 5) {
    int jj = tt * 4 + (col >> 2);     // hidden unit
    int gp = col & 3;                 // gate part i/f/g/o
    if (jj < H_N && k < H_N) v = f2bf(ps[w][((size_t)gp * H_N + jj) * H_N + k]);
  } else {
    int gate = tt * 16 + col;
    if (gate < FH_N && k < H_N) v = f2bf(ps[w][(size_t)gate * H_N + k]);
  }
  dst[i] = v;
}

// ---------------------------------------------------------------------------
// Kernel 0b: bitonic sort of sentence ids by length (desc) -> order[]
// ---------------------------------------------------------------------------
__global__ __launch_bounds__(1024) void k_sort(
    const int* __restrict__ lengths, int* __restrict__ order)
{
  __shared__ int key[2048], val[2048];
  int tid = threadIdx.x;
  for (int v = 0; v < 2; ++v) {
    int i = tid + v * 1024;
    key[i] = (i < S_N) ? lengths[i] : -1;
    val[i] = (i < S_N) ? i : (S_N - 1);
  }
  __syncthreads();
  for (int k = 2; k <= 2048; k <<= 1)
    for (int j = k >> 1; j > 0; j >>= 1) {
      for (int v = 0; v < 2; ++v) {
        int i = tid + v * 1024;
        int ix = i ^ j;
        if (ix > i) {
          bool descRegion = ((i & k) == 0);
          int ki = key[i], kx = key[ix];
          if ((ki < kx) == descRegion) {
            key[i] = kx; key[ix] = ki;
            int tv = val[i]; val[i] = val[ix]; val[ix] = tv;
          }
        }
      }
      __syncthreads();
    }
  for (int v = 0; v < 2; ++v) {
    int i = tid + v * 1024;
    if (i < S_N) order[i] = val[i];
  }
}

// ---------------------------------------------------------------------------
// Kernel X: chunked input-projection GEMM (conflict-free staging layout).
// gxc[slot][tc][gate] = words[s][c*CH+tc] @ wih^T + (bih+bhh).
// slot 0..1024 = ctx on sentence slot; slot 1025 = tgt on MID.
// ---------------------------------------------------------------------------
__global__ __launch_bounds__(512, 1) void k_xpack(
    int c, int CH,
    const float* __restrict__ words, const int* __restrict__ lengths,
    const u16* __restrict__ wihb_ctx, const float* __restrict__ bih_ctx, const float* __restrict__ bhh_ctx,
    const u16* __restrict__ wihb_tgt, const float* __restrict__ bih_tgt, const float* __restrict__ bhh_tgt,
    float* __restrict__ gxc)
{
  const int slot = blockIdx.x % 1026;
  const int tile = blockIdx.x / 1026;
  const int t0f = tile * 16;
  const bool tg = (slot == 1025);
  const int s = tg ? MID : slot;
  const int len = lengths[s];
  const int tbase = c * CH + t0f;
  if (t0f >= CH || tbase >= len) return;
  const u16* wih = tg ? wihb_tgt : wihb_ctx;
  const float* bih = tg ? bih_tgt : bih_ctx;
  const float* bhh = tg ? bhh_tgt : bhh_ctx;

  __shared__ __align__(16) u16 sXh[FRAGSZ];
  __shared__ __align__(16) u16 sXl[FRAGSZ];
  __shared__ float sBias[FH_N];
  const int tid = threadIdx.x;
  for (int e = tid; e < FRAGSZ; e += 512) { sXh[e] = 0; sXl[e] = 0; }
  for (int e = tid; e < FH_N; e += 512) sBias[e] = bih[e] + bhh[e];
  __syncthreads();
  const int nrow = min(16, min(CH - t0f, len - tbase));
  for (int e = tid; e < nrow * H_N; e += 512) {
    int tr = e / H_N, k = e - tr * H_N;
    float v = words[((size_t)s * W_N + tbase + tr) * H_N + k];
    u16 vh = f2bf(v);
    int idx = fidx(tr, k);
    sXh[idx] = vh;
    sXl[idx] = f2bf(v - bf2f(vh));
  }
  __syncthreads();

  const int lane = tid & 63, wv = tid >> 6, quad = lane >> 4, col = lane & 15;
  const int tcg = t0f + col;
  const bool okcol = (tcg < CH) && (c * CH + tcg < len);

#pragma unroll
  for (int i = 0; i < 7; ++i) {
    int tt = wv + 8 * i;
    if (tt < 50) {                      // wave-uniform: skip pad tiles
      f32x4 acc = {0.f, 0.f, 0.f, 0.f};
#pragma unroll
      for (int kcc = 0; kcc < 7; ++kcc) {
        bf16x8 Aw = *pkptr(wih, tt, kcc, lane);
        bf16x8 bxh = *frg(sXh, kcc, lane);
        bf16x8 bxl = *frg(sXl, kcc, lane);
        acc = __builtin_amdgcn_mfma_f32_16x16x32_bf16(Aw, bxh, acc, 0, 0, 0);
        acc = __builtin_amdgcn_mfma_f32_16x16x32_bf16(Aw, bxl, acc, 0, 0, 0);
      }
      if (okcol) {
        float b0 = sBias[tt * 16 + quad * 4 + 0];
        float b1 = sBias[tt * 16 + quad * 4 + 1];
        float b2 = sBias[tt * 16 + quad * 4 + 2];
        float b3 = sBias[tt * 16 + quad * 4 + 3];
        f32x4 o = {acc[0] + b0, acc[1] + b1, acc[2] + b2, acc[3] + b3};
        *(f32x4*)(gxc + ((size_t)slot * CH + tcg) * FH_N + tt * 16 + quad * 4) = o;
      }
    }
  }
}

// ---------------------------------------------------------------------------
// Kernel R: chunked word-level recurrence. whh register/AGPR-resident
// afr[7][7]; B = 16 sentences' h (hi/lo) in the conflict-free frag layout.
// gx loads issued after acc->sG (acc regs freed), consumed post-barrier.
// ---------------------------------------------------------------------------
__global__ __launch_bounds__(512, 1) void k_wrec(
    int c, int CH,
    const int* __restrict__ lengths, const int* __restrict__ order,
    const float* __restrict__ h0w, const float* __restrict__ c0w,
    const u16* __restrict__ whhb_ctx, const u16* __restrict__ whhb_tgt,
    const float* __restrict__ gxc,
    float* __restrict__ stateH, float* __restrict__ stateC,
    float* __restrict__ emb)
{
  const int tid = threadIdx.x;
  const int b = blockIdx.x;
  const bool is_tgt = (b == 65);
  const u16* whh = is_tgt ? whhb_tgt : whhb_ctx;

  __shared__ __align__(16) u16 sBh[FRAGSZ];
  __shared__ __align__(16) u16 sBl[FRAGSZ];
  __shared__ float sG[16 * SGW];
  __shared__ int sLen[16], sId[16];

  if (tid < 16) {
    int slot = b * 16 + tid;
    int s = is_tgt ? MID : order[min(slot, S_N - 1)];
    sId[tid] = s;
    sLen[tid] = lengths[s];
  }
  __syncthreads();
  int Lmax = 1;
  for (int m = 0; m < 16; ++m) Lmax = max(Lmax, sLen[m]);
  if (c * CH >= Lmax) return;

  const int lane = tid & 63;
  const int wv = tid >> 6;
  const int quad = lane >> 4;
  const int col = lane & 15;

  bf16x8 afr[7][7];
#pragma unroll
  for (int i = 0; i < 7; ++i)
#pragma unroll
    for (int kcc = 0; kcc < 7; ++kcc)
      afr[i][kcc] = *pkptr(whh, wv + 8 * i, kcc, lane);

  for (int e = tid; e < FRAGSZ; e += 512) { sBh[e] = 0; sBl[e] = 0; }
  __syncthreads();

  float creg[7];
#pragma unroll
  for (int rr = 0; rr < 7; ++rr) {
    int e = tid + 512 * rr;
    if (e < 16 * H_N) {
      int m = e / H_N, j = e - m * H_N;
      float h, cc;
      if (c == 0) {
        int s = sId[m];
        h = h0w[(size_t)s * H_N + j];
        cc = c0w[(size_t)s * H_N + j];
      } else {
        h = stateH[(size_t)(b * 16 + m) * H_N + j];
        cc = stateC[(size_t)(b * 16 + m) * H_N + j];
      }
      creg[rr] = cc;
      u16 hh = f2bf(h);
      int idx = fidx(m, j);
      sBh[idx] = hh;
      sBl[idx] = f2bf(h - bf2f(hh));
    }
  }
  __syncthreads();

#pragma unroll 1
  for (int tc = 0; tc < CH; ++tc) {
    const int t = c * CH + tc;
    if (t >= Lmax) break;

    f32x4 acc[7];
#pragma unroll
    for (int i = 0; i < 7; ++i) { f32x4 z = {0.f, 0.f, 0.f, 0.f}; acc[i] = z; }
#pragma unroll
    for (int kcc = 0; kcc < 7; ++kcc) {
      bf16x8 bh = *frg(sBh, kcc, lane);
      bf16x8 bl = *frg(sBl, kcc, lane);
#pragma unroll
      for (int i = 0; i < 7; ++i) {
        if (wv + 8 * i < 50) {          // wave-uniform: skip pad tiles
          acc[i] = __builtin_amdgcn_mfma_f32_16x16x32_bf16(afr[i][kcc], bh, acc[i], 0, 0, 0);
          acc[i] = __builtin_amdgcn_mfma_f32_16x16x32_bf16(afr[i][kcc], bl, acc[i], 0, 0, 0);
        }
      }
    }
#pragma unroll
    for (int i = 0; i < 7; ++i) {
      int tt = wv + 8 * i;
      if (tt < 50)
        *(f32x4*)(sG + col * SGW + tt * 16 + quad * 4) = acc[i];
    }

    // issue gx loads now (acc freed); latency overlaps the barrier drain
    float gv[7][4];
#pragma unroll
    for (int rr = 0; rr < 7; ++rr) {
      int e = tid + 512 * rr;
      if (e < 16 * H_N) {
        int m = e / H_N, j = e - m * H_N;
        int gslot = is_tgt ? 1025 : sId[m];
        const float* gp = gxc + ((size_t)gslot * CH + tc) * FH_N + j;
        gv[rr][0] = gp[0];
        gv[rr][1] = gp[H_N];
        gv[rr][2] = gp[2 * H_N];
        gv[rr][3] = gp[3 * H_N];
      }
    }
    __syncthreads();

#pragma unroll
    for (int rr = 0; rr < 7; ++rr) {
      int e = tid + 512 * rr;
      if (e < 16 * H_N) {
        int m = e / H_N, j = e - m * H_N;
        const float* gRow = sG + m * SGW + j;
        float ig = gRow[0] + gv[rr][0];
        float fg = gRow[H_N] + gv[rr][1];
        float gg = gRow[2 * H_N] + gv[rr][2];
        float og = gRow[3 * H_N] + gv[rr][3];
        float nc = fsigm(fg) * creg[rr] + fsigm(ig) * ftanh(gg);
        float nh = fsigm(og) * ftanh(nc);
        creg[rr] = nc;
        u16 hh = f2bf(nh);
        int idx = fidx(m, j);
        sBh[idx] = hh;
        sBl[idx] = f2bf(nh - bf2f(hh));
        if (t == sLen[m] - 1) {
          int s = sId[m];
          if (is_tgt) {
            if (m == 0) emb[(size_t)MID * H_N + j] = nh;
          } else if (s != MID) {
            emb[(size_t)s * H_N + j] = nh;
          }
        }
      }
    }
    __syncthreads();
  }

#pragma unroll
  for (int rr = 0; rr < 7; ++rr) {
    int e = tid + 512 * rr;
    if (e < 16 * H_N) {
      int m = e / H_N, j = e - m * H_N;
      int idx = fidx(m, j);
      stateH[(size_t)(b * 16 + m) * H_N + j] = bf2f(sBh[idx]) + bf2f(sBl[idx]);
      stateC[(size_t)(b * 16 + m) * H_N + j] = creg[rr];
    }
  }
}

// ---------------------------------------------------------------------------
// Fallback (tiny ws): streaming word kernel (round-5 style, unchanged).
// ---------------------------------------------------------------------------
__global__ __launch_bounds__(512, 1) void k_word_s(
    const float* __restrict__ words, const int* __restrict__ lengths,
    const int* __restrict__ order,
    const float* __restrict__ h0w, const float* __restrict__ c0w,
    const u16* __restrict__ wihb_ctx, const u16* __restrict__ whhb_ctx,
    const float* __restrict__ bih_ctx, const float* __restrict__ bhh_ctx,
    const u16* __restrict__ wihb_tgt, const u16* __restrict__ whhb_tgt,
    const float* __restrict__ bih_tgt, const float* __restrict__ bhh_tgt,
    float* __restrict__ emb)
{
  const int tid = threadIdx.x;
  const int b = blockIdx.x;
  const bool is_tgt = (b == 65);
  const u16* wih = is_tgt ? wihb_tgt : wihb_ctx;
  const u16* whh = is_tgt ? whhb_tgt : whhb_ctx;
  const float* bih = is_tgt ? bih_tgt : bih_ctx;
  const float* bhh = is_tgt ? bhh_tgt : bhh_ctx;

  __shared__ __align__(16) u16 sXhi[16 * KP];
  __shared__ __align__(16) u16 sXlo[16 * KP];
  __shared__ __align__(16) u16 sHi[16 * KP];
  __shared__ __align__(16) u16 sLo[16 * KP];
  __shared__ float sG[8 * SGP];
  __shared__ float sB[4 * H_N];
  __shared__ int sLen[16], sId[16];

  for (int e = tid; e < 16 * KP; e += 512) {
    sXhi[e] = 0; sXlo[e] = 0; sHi[e] = 0; sLo[e] = 0;
  }
  if (tid < 16) {
    int slot = b * 16 + tid;
    int s = is_tgt ? MID : order[min(slot, S_N - 1)];
    sId[tid] = s;
    sLen[tid] = lengths[s];
  }
  for (int e = tid; e < 4 * H_N; e += 512) sB[e] = bih[e] + bhh[e];
  __syncthreads();

  float creg[7];
#pragma unroll
  for (int r = 0; r < 7; ++r) {
    int e = tid + 512 * r;
    if (e < 16 * H_N) {
      int m = e / H_N, j = e - m * H_N;
      int s = sId[m];
      float h = h0w[(size_t)s * H_N + j];
      u16 hh = f2bf(h);
      sHi[m * KP + j] = hh;
      sLo[m * KP + j] = f2bf(h - bf2f(hh));
      creg[r] = c0w[(size_t)s * H_N + j];
    }
  }
  __syncthreads();
  int Lmax = 1;
  for (int m = 0; m < 16; ++m) Lmax = max(Lmax, sLen[m]);

  const int lane = tid & 63;
  const int wv = tid >> 6;
  const int quad = lane >> 4;
  const int col = lane & 15;
  const int hpass = quad >> 1;

  const u16* aXh = sXhi + col * KP + quad * 8;
  const u16* aXl = sXlo + col * KP + quad * 8;
  const u16* aHh = sHi  + col * KP + quad * 8;
  const u16* aHl = sLo  + col * KP + quad * 8;

#pragma unroll 1
  for (int t = 0; t < Lmax; ++t) {
    for (int e = tid; e < 16 * H_N; e += 512) {
      int m = e / H_N, k = e - m * H_N;
      float v = words[((size_t)sId[m] * W_N + t) * H_N + k];
      u16 vh = f2bf(v);
      sXhi[m * KP + k] = vh;
      sXlo[m * KP + k] = f2bf(v - bf2f(vh));
    }
    __syncthreads();

    f32x4 acc[7];
#pragma unroll
    for (int i = 0; i < 7; ++i) { f32x4 z4 = {0.f, 0.f, 0.f, 0.f}; acc[i] = z4; }

#pragma unroll
    for (int kcc = 0; kcc < 7; ++kcc) {
      bf16x8 axh = *(const bf16x8*)(aXh + kcc * 32);
      bf16x8 axl = *(const bf16x8*)(aXl + kcc * 32);
      bf16x8 ahh = *(const bf16x8*)(aHh + kcc * 32);
      bf16x8 ahl = *(const bf16x8*)(aHl + kcc * 32);
#pragma unroll
      for (int i = 0; i < 7; ++i) {
        if (wv + 8 * i < 50) {
          bf16x8 bw = *pkptr(wih, wv + 8 * i, kcc, lane);
          bf16x8 bh = *pkptr(whh, wv + 8 * i, kcc, lane);
          acc[i] = __builtin_amdgcn_mfma_f32_16x16x32_bf16(axh, bw, acc[i], 0, 0, 0);
          acc[i] = __builtin_amdgcn_mfma_f32_16x16x32_bf16(axl, bw, acc[i], 0, 0, 0);
          acc[i] = __builtin_amdgcn_mfma_f32_16x16x32_bf16(ahh, bh, acc[i], 0, 0, 0);
          acc[i] = __builtin_amdgcn_mfma_f32_16x16x32_bf16(ahl, bh, acc[i], 0, 0, 0);
        }
      }
    }

#pragma unroll 1
    for (int h = 0; h < 2; ++h) {
      if (hpass == h) {
#pragma unroll
        for (int i = 0; i < 7; ++i) {
          int tt = wv + 8 * i;
          if (tt < 50) {
#pragma unroll
            for (int r = 0; r < 4; ++r)
              sG[((quad & 1) * 4 + r) * SGP + tt * 16 + col] = acc[i][r];
          }
        }
      }
      __syncthreads();
#pragma unroll
      for (int rr = 0; rr < 7; ++rr) {
        int e = tid + 512 * rr;
        if (e < 16 * H_N) {
          int m = e / H_N, j = e - m * H_N;
          if ((m >> 3) == h) {
            const float* gRow = sG + (m - 8 * h) * SGP;
            float ig = gRow[j] + sB[j];
            float fg = gRow[H_N + j] + sB[H_N + j];
            float gg = gRow[2 * H_N + j] + sB[2 * H_N + j];
            float og = gRow[3 * H_N + j] + sB[3 * H_N + j];
            float nc = fsigm(fg) * creg[rr] + fsigm(ig) * ftanh(gg);
            float nh = fsigm(og) * ftanh(nc);
            creg[rr] = nc;
            u16 hh = f2bf(nh);
            sHi[m * KP + j] = hh;
            sLo[m * KP + j] = f2bf(nh - bf2f(hh));
            if (t == sLen[m] - 1) {
              int s = sId[m];
              if (is_tgt) {
                if (m == 0) emb[(size_t)MID * H_N + j] = nh;
              } else if (s != MID) {
                emb[(size_t)s * H_N + j] = nh;
              }
            }
          }
        }
      }
      __syncthreads();
    }
  }
}

// ---------------------------------------------------------------------------
// Kernel 2: gx projections for prev/post via MFMA (packed wih).
// Output layout INTERLEAVED for k_sent: gx[t][j*4 + gate], gate 0..3=i,f,g,o.
// ---------------------------------------------------------------------------
__global__ __launch_bounds__(512) void k_gx(
    const float* __restrict__ emb,
    const u16* __restrict__ wihb_prev, const float* __restrict__ bih_prev, const float* __restrict__ bhh_prev,
    const u16* __restrict__ wihb_post, const float* __restrict__ bih_post, const float* __restrict__ bhh_post,
    float* __restrict__ gxp, float* __restrict__ gxq)
{
  const int tid = threadIdx.x;
  const int b = blockIdx.x;
  const bool post = (b >= 33);
  const int t0 = (post ? b - 33 : b) * 16;
  const u16* wih = post ? wihb_post : wihb_prev;
  const float* bih = post ? bih_post : bih_prev;
  const float* bhh = post ? bhh_post : bhh_prev;
  float* out = post ? gxq : gxp;

  __shared__ __align__(16) u16 sEhi[16 * KP];
  __shared__ __align__(16) u16 sElo[16 * KP];
  for (int e = tid; e < 16 * KP; e += 512) { sEhi[e] = 0; sElo[e] = 0; }
  __syncthreads();
  for (int e = tid; e < 16 * H_N; e += 512) {
    int m = e / H_N, k = e - m * H_N;
    int t = t0 + m;
    if (t <= 512) {
      int src = post ? (1024 - t) : t;
      float v = emb[(size_t)src * H_N + k];
      u16 vh = f2bf(v);
      sEhi[m * KP + k] = vh;
      sElo[m * KP + k] = f2bf(v - bf2f(vh));
    }
  }
  __syncthreads();

  const int lane = tid & 63;
  const int wv = tid >> 6;
  const int quad = lane >> 4;
  const int col = lane & 15;
  const u16* aH = sEhi + col * KP + quad * 8;
  const u16* aL = sElo + col * KP + quad * 8;

#pragma unroll 1
  for (int i = 0; i < 7; ++i) {
    int tt = wv + 8 * i;
    if (tt >= 50) break;
    int gate = tt * 16 + col;
    f32x4 acc = {0.f, 0.f, 0.f, 0.f};
#pragma unroll
    for (int kcc = 0; kcc < 7; ++kcc) {
      bf16x8 Ah = *(const bf16x8*)(aH + kcc * 32);
      bf16x8 Al = *(const bf16x8*)(aL + kcc * 32);
      bf16x8 bw = *pkptr(wih, tt, kcc, lane);
      acc = __builtin_amdgcn_mfma_f32_16x16x32_bf16(Ah, bw, acc, 0, 0, 0);
      acc = __builtin_amdgcn_mfma_f32_16x16x32_bf16(Al, bw, acc, 0, 0, 0);
    }
    float bias = bih[gate] + bhh[gate];
    int gp = gate >= 600 ? 3 : (gate >= 400 ? 2 : (gate >= 200 ? 1 : 0));
    int jg = gate - gp * 200;
#pragma unroll
    for (int r = 0; r < 4; ++r) {
      int t = t0 + quad * 4 + r;
      if (t <= 512) out[(size_t)t * FH_N + jg * 4 + gp] = acc[r] + bias;
    }
  }
}

// ---------------------------------------------------------------------------
// Kernel 3: prev/post sentence LSTMs, 513 serial steps.
// 256 threads, 1 wave/SIMD. Weight placement (round-4 post-mortem):
//   - tiles tt = wv+4*i, i=0..7 (32 tiles): asm AGPR, 8x7=56 frag = 224 AGPR
//     <= 256 WITH 32 REGS SLACK (round-4's 252 left no room for the RA's
//     builtin-acc AGPR preference -> oversubscription -> mid-loop AGPR
//     spills around opaque asm -> wrong results).
//   - tiles tt = 32..49 (18 tiles): staged ONCE into LDS (126 KB), read per
//     step via ds_read + builtin MFMA (compiler-managed hazards).
// Cluster order: asm first, then sched_barrier, then the builtin-LDS cluster
// (~300 cyc natural drain for asm results), then sched_barrier + 6x s_nop 7
// before any read of acc. VGPR side only transients (~130 regs, no spill).
// Gate-interleaved whh packing: each lane's f32x4 acc = (i,f,g,o) of hidden
// unit j = tt*4+quad; hi/lo via B-column trick (cols 0-7 hi, 8-15 lo).
// ---------------------------------------------------------------------------
__global__ __launch_bounds__(256, 1) void k_sent(
    const u16* __restrict__ whhb_prev, const u16* __restrict__ whhb_post,
    const float* __restrict__ h0p, const float* __restrict__ c0p,
    const float* __restrict__ h0q, const float* __restrict__ c0q,
    const float* __restrict__ gxp, const float* __restrict__ gxq,
    float* __restrict__ outp, float* __restrict__ outq)
{
  const int tid = threadIdx.x;
  const bool post = (blockIdx.x != 0);
  const u16* whh = post ? whhb_post : whhb_prev;
  const float* h0 = post ? h0q : h0p;
  const float* c0 = post ? c0q : c0p;
  const float* gx = post ? gxq : gxp;
  float* outv = post ? outq : outp;

  __shared__ __align__(16) u16 sHi[224];
  __shared__ __align__(16) u16 sLo[224];
  __shared__ __align__(16) float sGt[H_N * 8];       // [j][0..3]=hi, [4..7]=lo
  __shared__ __align__(16) u16 sW[18 * 7 * 512];     // weight tiles tt=32..49

  const int lane = tid & 63;
  const int wv = tid >> 6;
  const int quad = lane >> 4;
  const int col = lane & 15;

  // AGPR-resident tiles: tt = wv + 4*i, i=0..7 (covers 0..31, all real)
  bf16x8 afrA[8][7];
#pragma unroll
  for (int i = 0; i < 8; ++i)
#pragma unroll
    for (int kcc = 0; kcc < 7; ++kcc)
      afrA[i][kcc] = *pkptr(whh, wv + 4 * i, kcc, lane);

  // stage tiles 32..49 (126 KB) into LDS once; 16B per thread per iter
  {
    const uint4* src = (const uint4*)(whh + 32 * 7 * 512);
    uint4* dst = (uint4*)sW;
    for (int e = tid; e < 18 * 7 * 512 / 8; e += 256) dst[e] = src[e];
  }

  if (tid < 224) { sHi[tid] = 0; sLo[tid] = 0; }
  float c = 0.f, last_h = 0.f;
  if (tid < H_N) {
    float h = h0[tid];
    u16 hh = f2bf(h);
    sHi[tid] = hh;
    sLo[tid] = f2bf(h - bf2f(hh));
    c = c0[tid];
  }
  __syncthreads();

  const u16* hb = ((lane & 8) ? sLo : sHi) + quad * 8;
  const bool wr = ((col & 7) == 0);   // cols 0 (hi) and 8 (lo) write gates
  const int wroff = (col >> 1);       // 0 or 4 floats
  // LDS tiles for this wave: tt = 32 + wv + 4*li, li=0..nL-1
  const int nL = (wv < 2) ? 5 : 4;    // wv=2/3 li=4 would be tt=50/51 (pad)

  f32x4 gc = {0.f, 0.f, 0.f, 0.f};
  if (tid < H_N) gc = *(const f32x4*)(gx + (size_t)tid * 4);

#pragma unroll 1
  for (int t = 0; t < 513; ++t) {
    bf16x8 bfr[7];
#pragma unroll
    for (int kcc = 0; kcc < 7; ++kcc) bfr[kcc] = *(const bf16x8*)(hb + kcc * 32);

    // prefetch next step's gx; HBM/L2 latency hides under the MFMA phase
    f32x4 gn = {0.f, 0.f, 0.f, 0.f};
    if (t + 1 < 513 && tid < H_N)
      gn = *(const f32x4*)(gx + (size_t)(t + 1) * FH_N + tid * 4);

    // asm AGPR cluster first: zero-C first slice, accumulate after
    f32x4 acc[8];
#pragma unroll
    for (int i = 0; i < 8; ++i) MFMA_A_Z(acc[i], afrA[i][0], bfr[0]);
#pragma unroll
    for (int kcc = 1; kcc < 7; ++kcc)
#pragma unroll
      for (int i = 0; i < 8; ++i)
        MFMA_A(acc[i], afrA[i][kcc], bfr[kcc]);

    __builtin_amdgcn_sched_barrier(0);

    // builtin LDS cluster second: ~300 cyc of independent work acts as a
    // natural drain for the asm MFMA results (plus explicit nops below).
    f32x4 accL[5];
#pragma unroll
    for (int li = 0; li < 5; ++li) {
      f32x4 z = {0.f, 0.f, 0.f, 0.f};
      accL[li] = z;
      if (li < nL) {                   // wave-uniform
#pragma unroll
        for (int kcc = 0; kcc < 7; ++kcc) {
          bf16x8 aw = *(const bf16x8*)(sW + (size_t)(((wv + 4 * li) * 7 + kcc) * 512) + lane * 8);
          accL[li] = __builtin_amdgcn_mfma_f32_16x16x32_bf16(aw, bfr[kcc], accL[li], 0, 0, 0);
        }
      }
    }

    // explicit hazard drain before any read of asm-written acc
    __builtin_amdgcn_sched_barrier(0);
    asm volatile("s_nop 7\n\ts_nop 7\n\ts_nop 7\n\ts_nop 7\n\ts_nop 7\n\ts_nop 7" ::);
    __builtin_amdgcn_sched_barrier(0);

    if (wr) {
#pragma unroll
      for (int i = 0; i < 8; ++i) {
        int tt = wv + 4 * i;
        *(f32x4*)(sGt + (tt * 4 + quad) * 8 + wroff) = acc[i];
      }
#pragma unroll
      for (int li = 0; li < 5; ++li) {
        if (li < nL) {
          int tt = 32 + wv + 4 * li;
          *(f32x4*)(sGt + (tt * 4 + quad) * 8 + wroff) = accL[li];
        }
      }
    }
    __syncthreads();

    if (tid < H_N) {
      f32x4 ga = *(const f32x4*)(sGt + tid * 8);
      f32x4 gb = *(const f32x4*)(sGt + tid * 8 + 4);
      float ig = ga[0] + gb[0] + gc[0];
      float fg = ga[1] + gb[1] + gc[1];
      float gg = ga[2] + gb[2] + gc[2];
      float og = ga[3] + gb[3] + gc[3];
      float nc = fsigm(fg) * c + fsigm(ig) * ftanh(gg);
      float nh = fsigm(og) * ftanh(nc);
      c = nc;
      last_h = nh;
      u16 hh = f2bf(nh);
      sHi[tid] = hh;
      sLo[tid] = f2bf(nh - bf2f(hh));
    }
    gc = gn;
    __syncthreads();
  }
  if (tid < H_N) outv[tid] = last_h;
}

// ---------------------------------------------------------------------------
// Kernel 4: out = [prev_out ; post_out] @ fc_w^T + fc_b
// ---------------------------------------------------------------------------
__global__ __launch_bounds__(256) void k_fc(
    const float* __restrict__ pout, const float* __restrict__ qout,
    const float* __restrict__ fc_w, const float* __restrict__ fc_b,
    float* __restrict__ out)
{
  const int tid = threadIdx.x;
  if (tid < H_N) {
    float d = fc_b[tid];
    const float* wr = fc_w + (size_t)tid * 2 * H_N;
    for (int k = 0; k < H_N; ++k) d += pout[k] * wr[k];
    for (int k = 0; k < H_N; ++k) d += qout[k] * wr[H_N + k];
    out[tid] = d;
  }
}

extern "C" void kernel_launch(void* const* d_in, const int* in_sizes, int n_in,
                              void* d_out, int out_size, void* d_ws, size_t ws_size,
                              hipStream_t stream) {
  const float* words   = (const float*)d_in[0];
  const int*   lengths = (const int*)d_in[1];
  const float* h0w = (const float*)d_in[2];
  const float* c0w = (const float*)d_in[3];
  const float* h0p = (const float*)d_in[4];
  const float* c0p = (const float*)d_in[5];
  const float* h0q = (const float*)d_in[6];
  const float* c0q = (const float*)d_in[7];
  const float* wih_ctx = (const float*)d_in[8];
  const float* whh_ctx = (const float*)d_in[9];
  const float* bih_ctx = (const float*)d_in[10];
  const float* bhh_ctx = (const float*)d_in[11];
  const float* wih_tgt = (const float*)d_in[12];
  const float* whh_tgt = (const float*)d_in[13];
  const float* bih_tgt = (const float*)d_in[14];
  const float* bhh_tgt = (const float*)d_in[15];
  const float* wih_prev = (const float*)d_in[16];
  const float* whh_prev = (const float*)d_in[17];
  const float* bih_prev = (const float*)d_in[18];
  const float* bhh_prev = (const float*)d_in[19];
  const float* wih_post = (const float*)d_in[20];
  const float* whh_post = (const float*)d_in[21];
  const float* bih_post = (const float*)d_in[22];
  const float* bhh_post = (const float*)d_in[23];
  const float* fc_w = (const float*)d_in[24];
  const float* fc_b = (const float*)d_in[25];
  (void)in_sizes; (void)n_in; (void)out_size;

  const size_t FIXF = 1448600;
  int CH = 0;
  for (int cand = 32; cand >= 1; cand >>= 1) {
    size_t needB = ((size_t)1026 * cand * 800 + FIXF) * 4 + 1056 * 4 + (size_t)8 * PKT * 2 + 256;
    if (ws_size >= needB) { CH = cand; break; }
  }

  float* ws = (float*)d_ws;
  float *gxc, *stateH, *stateC, *emb, *gxp, *gxq, *po, *qo;
  int* order;
  u16* wb;
  if (CH > 0) {
    gxc = ws;
    stateH = gxc + (size_t)1026 * CH * 800;
    stateC = stateH + 211200;
    emb = stateC + 211200;
    gxp = emb + 205000;
    gxq = gxp + 410400;
    po = gxq + 410400;
    qo = po + 200;
    order = (int*)(qo + 200);
    wb = (u16*)(order + 1056);
  } else {
    gxc = nullptr; stateH = nullptr; stateC = nullptr;
    emb = ws;
    gxp = ws + 205000;
    gxq = ws + 615400;
    po = ws + 1025800;
    qo = ws + 1026000;
    order = (int*)(ws + 1026200);
    wb = (u16*)(ws + 1027232);
  }
  u16* wihb_ctx  = wb;
  u16* whhb_ctx  = wb + PKT;
  u16* wihb_tgt  = wb + 2 * PKT;
  u16* whhb_tgt  = wb + 3 * PKT;
  u16* whhb_prev = wb + 4 * PKT;
  u16* whhb_post = wb + 5 * PKT;
  u16* wihb_prev = wb + 6 * PKT;
  u16* wihb_post = wb + 7 * PKT;

  k_w2b<<<(8 * PKT + 255) / 256, 256, 0, stream>>>(
      wih_ctx, whh_ctx, wih_tgt, whh_tgt, whh_prev, whh_post,
      wih_prev, wih_post, wb);
  k_sort<<<1, 1024, 0, stream>>>(lengths, order);

  if (CH > 0) {
    const int TT = (CH + 15) / 16;
    const int NC = (W_N + CH - 1) / CH;
    for (int c = 0; c < NC; ++c) {
      k_xpack<<<1026 * TT, 512, 0, stream>>>(c, CH, words, lengths,
                                             wihb_ctx, bih_ctx, bhh_ctx,
                                             wihb_tgt, bih_tgt, bhh_tgt, gxc);
      k_wrec<<<66, 512, 0, stream>>>(c, CH, lengths, order, h0w, c0w,
                                     whhb_ctx, whhb_tgt, gxc, stateH, stateC, emb);
    }
  } else {
    k_word_s<<<66, 512, 0, stream>>>(words, lengths, order, h0w, c0w,
                                     wihb_ctx, whhb_ctx, bih_ctx, bhh_ctx,
                                     wihb_tgt, whhb_tgt, bih_tgt, bhh_tgt, emb);
  }
  k_gx<<<66, 512, 0, stream>>>(emb, wihb_prev, bih_prev, bhh_prev,
                               wihb_post, bih_post, bhh_post, gxp, gxq);
  k_sent<<<2, 256, 0, stream>>>(whhb_prev, whhb_post, h0p, c0p, h0q, c0q,
                                gxp, gxq, po, qo);
  k_fc<<<1, 256, 0, stream>>>(po, qo, fc_w, fc_b, (float*)d_out);
}

// Round 7
// 2012.702 us; speedup vs baseline: 1.5841x; 1.0475x over previous
//
#include <hip/hip_runtime.h>
#include <cmath>

typedef unsigned short u16;
typedef short bf16x8 __attribute__((ext_vector_type(8)));
typedef float f32x4 __attribute__((ext_vector_type(4)));

#define S_N 1025
#define W_N 128
#define H_N 200
#define FH_N 800
#define KP 232
#define SGP 911
#define SGW 804      // wrec sG row stride (floats); 804%32=4 stagger, gates<800
#define MID 512
#define NT 56
#define PKT (NT * 7 * 512)
// conflict-free LDS B-fragment layout: per-kcc stride 544 u16, per-quadk 136
#define PKC 544
#define QKS 136
#define FRAGSZ (7 * PKC)   // 3808 u16 per array

__device__ __forceinline__ float bf2f(u16 u) {
  unsigned int x = ((unsigned int)u) << 16;
  return __builtin_bit_cast(float, x);
}
__device__ __forceinline__ u16 f2bf(float f) {
  unsigned int x = __builtin_bit_cast(unsigned int, f);
  x += 0x7fffu + ((x >> 16) & 1u);
  return (u16)(x >> 16);
}
#define LOG2E 1.44269504088896f
__device__ __forceinline__ float fsigm(float x) {
  float e = __builtin_amdgcn_exp2f(-fabsf(x) * LOG2E);
  float p = __builtin_amdgcn_rcpf(1.f + e);
  return x >= 0.f ? p : 1.f - p;
}
__device__ __forceinline__ float ftanh(float x) {
  float e = __builtin_amdgcn_exp2f(-2.f * fabsf(x) * LOG2E);
  float th = (1.f - e) * __builtin_amdgcn_rcpf(1.f + e);
  return x >= 0.f ? th : -th;
}

__device__ __forceinline__ const bf16x8* pkptr(const u16* pk, int tt, int kcc, int lane) {
  return (const bf16x8*)(pk + (size_t)((tt * 7 + kcc) * 512 + lane * 8));
}
// writer: element (row m 0..15, k 0..199) -> padded LDS fragment index
__device__ __forceinline__ int fidx(int m, int k) {
  return (k >> 5) * PKC + ((k >> 3) & 3) * QKS + m * 8 + (k & 7);
}
// reader: lane's 16B fragment for k-chunk kcc (16B-aligned: QKS*2=272=17*16)
__device__ __forceinline__ const bf16x8* frg(const u16* base, int kcc, int lane) {
  return (const bf16x8*)(base + kcc * PKC + (lane >> 4) * QKS + (lane & 15) * 8);
}

// AGPR-pinned MFMA (asm "a" constraint). REGISTER MODEL (r2-r6, measured):
// per-wave budget = (VGPR+AGPR combined) = 512 / waves_per_SIMD; AGPR<=256;
// asm AGPR demand + RA's builtin-acc AGPR placement must fit WITH SLACK
// (r4: slack 4 -> wrong results; r5: slack ~12 passed; r6: infeasible 300/256
// -> wrong results). Hazards manual: sched_barrier + s_nop block between the
// asm MFMA cluster and any read of its acc (verified r3/r5).
#define MFMA_A_Z(acc, Aag, Bv)                                               \
  asm volatile("v_mfma_f32_16x16x32_bf16 %0, %1, %2, 0"                      \
      : "=&v"(acc) : "a"(Aag), "v"(Bv))
#define MFMA_A(acc, Aag, Bv)                                                 \
  asm volatile("v_mfma_f32_16x16x32_bf16 %0, %1, %2, %0"                     \
      : "+v"(acc) : "a"(Aag), "v"(Bv))

// ---------------------------------------------------------------------------
// Kernel 0: repack 8 fp32 weight matrices to bf16 MFMA fragment order.
// dst: [wih_ctx|whh_ctx|wih_tgt|whh_tgt|whh_prev|whh_post|wih_prev|wih_post]
// w==4/5 (whh_prev/whh_post, consumed only by k_sent) use GATE-INTERLEAVED
// rows: A-row16 = j_local*4 + gate, so each k_sent lane's f32x4 acc is the
// (i,f,g,o) gates of a single hidden unit.
// ---------------------------------------------------------------------------
__global__ __launch_bounds__(256) void k_w2b(
    const float* __restrict__ p0, const float* __restrict__ p1,
    const float* __restrict__ p2, const float* __restrict__ p3,
    const float* __restrict__ p4, const float* __restrict__ p5,
    const float* __restrict__ p6, const float* __restrict__ p7,
    u16* __restrict__ dst)
{
  int i = blockIdx.x * 256 + threadIdx.x;
  if (i >= 8 * PKT) return;
  int w = i / PKT, r = i - w * PKT;
  int tt = r / 3584;
  int q = r - tt * 3584;
  int kcc = q >> 9;
  int lane = (q >> 3) & 63;
  int j = q & 7;
  int col = lane & 15, quad = lane >> 4;
  int k = kcc * 32 + quad * 8 + j;
  const float* ps[8] = {p0, p1, p2, p3, p4, p5, p6, p7};
  u16 v = 0;
  if (w == 4 || w == 5) {
    int jj = tt * 4 + (col >> 2);     // hidden unit
    int gp = col & 3;                 // gate part i/f/g/o
    if (jj < H_N && k < H_N) v = f2bf(ps[w][((size_t)gp * H_N + jj) * H_N + k]);
  } else {
    int gate = tt * 16 + col;
    if (gate < FH_N && k < H_N) v = f2bf(ps[w][(size_t)gate * H_N + k]);
  }
  dst[i] = v;
}

// ---------------------------------------------------------------------------
// Kernel 0b: bitonic sort of sentence ids by length (desc) -> order[]
// ---------------------------------------------------------------------------
__global__ __launch_bounds__(1024) void k_sort(
    const int* __restrict__ lengths, int* __restrict__ order)
{
  __shared__ int key[2048], val[2048];
  int tid = threadIdx.x;
  for (int v = 0; v < 2; ++v) {
    int i = tid + v * 1024;
    key[i] = (i < S_N) ? lengths[i] : -1;
    val[i] = (i < S_N) ? i : (S_N - 1);
  }
  __syncthreads();
  for (int k = 2; k <= 2048; k <<= 1)
    for (int j = k >> 1; j > 0; j >>= 1) {
      for (int v = 0; v < 2; ++v) {
        int i = tid + v * 1024;
        int ix = i ^ j;
        if (ix > i) {
          bool descRegion = ((i & k) == 0);
          int ki = key[i], kx = key[ix];
          if ((ki < kx) == descRegion) {
            key[i] = kx; key[ix] = ki;
            int tv = val[i]; val[i] = val[ix]; val[ix] = tv;
          }
        }
      }
      __syncthreads();
    }
  for (int v = 0; v < 2; ++v) {
    int i = tid + v * 1024;
    if (i < S_N) order[i] = val[i];
  }
}

// ---------------------------------------------------------------------------
// Kernel X: chunked input-projection GEMM (conflict-free staging layout).
// gxc[slot][tc][gate] = words[s][c*CH+tc] @ wih^T + (bih+bhh).
// slot 0..1024 = ctx on sentence slot; slot 1025 = tgt on MID.
// ---------------------------------------------------------------------------
__global__ __launch_bounds__(512, 1) void k_xpack(
    int c, int CH,
    const float* __restrict__ words, const int* __restrict__ lengths,
    const u16* __restrict__ wihb_ctx, const float* __restrict__ bih_ctx, const float* __restrict__ bhh_ctx,
    const u16* __restrict__ wihb_tgt, const float* __restrict__ bih_tgt, const float* __restrict__ bhh_tgt,
    float* __restrict__ gxc)
{
  const int slot = blockIdx.x % 1026;
  const int tile = blockIdx.x / 1026;
  const int t0f = tile * 16;
  const bool tg = (slot == 1025);
  const int s = tg ? MID : slot;
  const int len = lengths[s];
  const int tbase = c * CH + t0f;
  if (t0f >= CH || tbase >= len) return;
  const u16* wih = tg ? wihb_tgt : wihb_ctx;
  const float* bih = tg ? bih_tgt : bih_ctx;
  const float* bhh = tg ? bhh_tgt : bhh_ctx;

  __shared__ __align__(16) u16 sXh[FRAGSZ];
  __shared__ __align__(16) u16 sXl[FRAGSZ];
  __shared__ float sBias[FH_N];
  const int tid = threadIdx.x;
  for (int e = tid; e < FRAGSZ; e += 512) { sXh[e] = 0; sXl[e] = 0; }
  for (int e = tid; e < FH_N; e += 512) sBias[e] = bih[e] + bhh[e];
  __syncthreads();
  const int nrow = min(16, min(CH - t0f, len - tbase));
  for (int e = tid; e < nrow * H_N; e += 512) {
    int tr = e / H_N, k = e - tr * H_N;
    float v = words[((size_t)s * W_N + tbase + tr) * H_N + k];
    u16 vh = f2bf(v);
    int idx = fidx(tr, k);
    sXh[idx] = vh;
    sXl[idx] = f2bf(v - bf2f(vh));
  }
  __syncthreads();

  const int lane = tid & 63, wv = tid >> 6, quad = lane >> 4, col = lane & 15;
  const int tcg = t0f + col;
  const bool okcol = (tcg < CH) && (c * CH + tcg < len);

#pragma unroll
  for (int i = 0; i < 7; ++i) {
    int tt = wv + 8 * i;
    if (tt < 50) {                      // wave-uniform: skip pad tiles
      f32x4 acc = {0.f, 0.f, 0.f, 0.f};
#pragma unroll
      for (int kcc = 0; kcc < 7; ++kcc) {
        bf16x8 Aw = *pkptr(wih, tt, kcc, lane);
        bf16x8 bxh = *frg(sXh, kcc, lane);
        bf16x8 bxl = *frg(sXl, kcc, lane);
        acc = __builtin_amdgcn_mfma_f32_16x16x32_bf16(Aw, bxh, acc, 0, 0, 0);
        acc = __builtin_amdgcn_mfma_f32_16x16x32_bf16(Aw, bxl, acc, 0, 0, 0);
      }
      if (okcol) {
        float b0 = sBias[tt * 16 + quad * 4 + 0];
        float b1 = sBias[tt * 16 + quad * 4 + 1];
        float b2 = sBias[tt * 16 + quad * 4 + 2];
        float b3 = sBias[tt * 16 + quad * 4 + 3];
        f32x4 o = {acc[0] + b0, acc[1] + b1, acc[2] + b2, acc[3] + b3};
        *(f32x4*)(gxc + ((size_t)slot * CH + tcg) * FH_N + tt * 16 + quad * 4) = o;
      }
    }
  }
}

// ---------------------------------------------------------------------------
// Kernel R: chunked word-level recurrence. whh register/AGPR-resident
// afr[7][7]; B = 16 sentences' h (hi/lo) in the conflict-free frag layout.
// gx loads issued after acc->sG (acc regs freed), consumed post-barrier.
// ---------------------------------------------------------------------------
__global__ __launch_bounds__(512, 1) void k_wrec(
    int c, int CH,
    const int* __restrict__ lengths, const int* __restrict__ order,
    const float* __restrict__ h0w, const float* __restrict__ c0w,
    const u16* __restrict__ whhb_ctx, const u16* __restrict__ whhb_tgt,
    const float* __restrict__ gxc,
    float* __restrict__ stateH, float* __restrict__ stateC,
    float* __restrict__ emb)
{
  const int tid = threadIdx.x;
  const int b = blockIdx.x;
  const bool is_tgt = (b == 65);
  const u16* whh = is_tgt ? whhb_tgt : whhb_ctx;

  __shared__ __align__(16) u16 sBh[FRAGSZ];
  __shared__ __align__(16) u16 sBl[FRAGSZ];
  __shared__ float sG[16 * SGW];
  __shared__ int sLen[16], sId[16];

  if (tid < 16) {
    int slot = b * 16 + tid;
    int s = is_tgt ? MID : order[min(slot, S_N - 1)];
    sId[tid] = s;
    sLen[tid] = lengths[s];
  }
  __syncthreads();
  int Lmax = 1;
  for (int m = 0; m < 16; ++m) Lmax = max(Lmax, sLen[m]);
  if (c * CH >= Lmax) return;

  const int lane = tid & 63;
  const int wv = tid >> 6;
  const int quad = lane >> 4;
  const int col = lane & 15;

  bf16x8 afr[7][7];
#pragma unroll
  for (int i = 0; i < 7; ++i)
#pragma unroll
    for (int kcc = 0; kcc < 7; ++kcc)
      afr[i][kcc] = *pkptr(whh, wv + 8 * i, kcc, lane);

  for (int e = tid; e < FRAGSZ; e += 512) { sBh[e] = 0; sBl[e] = 0; }
  __syncthreads();

  float creg[7];
#pragma unroll
  for (int rr = 0; rr < 7; ++rr) {
    int e = tid + 512 * rr;
    if (e < 16 * H_N) {
      int m = e / H_N, j = e - m * H_N;
      float h, cc;
      if (c == 0) {
        int s = sId[m];
        h = h0w[(size_t)s * H_N + j];
        cc = c0w[(size_t)s * H_N + j];
      } else {
        h = stateH[(size_t)(b * 16 + m) * H_N + j];
        cc = stateC[(size_t)(b * 16 + m) * H_N + j];
      }
      creg[rr] = cc;
      u16 hh = f2bf(h);
      int idx = fidx(m, j);
      sBh[idx] = hh;
      sBl[idx] = f2bf(h - bf2f(hh));
    }
  }
  __syncthreads();

#pragma unroll 1
  for (int tc = 0; tc < CH; ++tc) {
    const int t = c * CH + tc;
    if (t >= Lmax) break;

    f32x4 acc[7];
#pragma unroll
    for (int i = 0; i < 7; ++i) { f32x4 z = {0.f, 0.f, 0.f, 0.f}; acc[i] = z; }
#pragma unroll
    for (int kcc = 0; kcc < 7; ++kcc) {
      bf16x8 bh = *frg(sBh, kcc, lane);
      bf16x8 bl = *frg(sBl, kcc, lane);
#pragma unroll
      for (int i = 0; i < 7; ++i) {
        if (wv + 8 * i < 50) {          // wave-uniform: skip pad tiles
          acc[i] = __builtin_amdgcn_mfma_f32_16x16x32_bf16(afr[i][kcc], bh, acc[i], 0, 0, 0);
          acc[i] = __builtin_amdgcn_mfma_f32_16x16x32_bf16(afr[i][kcc], bl, acc[i], 0, 0, 0);
        }
      }
    }
#pragma unroll
    for (int i = 0; i < 7; ++i) {
      int tt = wv + 8 * i;
      if (tt < 50)
        *(f32x4*)(sG + col * SGW + tt * 16 + quad * 4) = acc[i];
    }

    // issue gx loads now (acc freed); latency overlaps the barrier drain
    float gv[7][4];
#pragma unroll
    for (int rr = 0; rr < 7; ++rr) {
      int e = tid + 512 * rr;
      if (e < 16 * H_N) {
        int m = e / H_N, j = e - m * H_N;
        int gslot = is_tgt ? 1025 : sId[m];
        const float* gp = gxc + ((size_t)gslot * CH + tc) * FH_N + j;
        gv[rr][0] = gp[0];
        gv[rr][1] = gp[H_N];
        gv[rr][2] = gp[2 * H_N];
        gv[rr][3] = gp[3 * H_N];
      }
    }
    __syncthreads();

#pragma unroll
    for (int rr = 0; rr < 7; ++rr) {
      int e = tid + 512 * rr;
      if (e < 16 * H_N) {
        int m = e / H_N, j = e - m * H_N;
        const float* gRow = sG + m * SGW + j;
        float ig = gRow[0] + gv[rr][0];
        float fg = gRow[H_N] + gv[rr][1];
        float gg = gRow[2 * H_N] + gv[rr][2];
        float og = gRow[3 * H_N] + gv[rr][3];
        float nc = fsigm(fg) * creg[rr] + fsigm(ig) * ftanh(gg);
        float nh = fsigm(og) * ftanh(nc);
        creg[rr] = nc;
        u16 hh = f2bf(nh);
        int idx = fidx(m, j);
        sBh[idx] = hh;
        sBl[idx] = f2bf(nh - bf2f(hh));
        if (t == sLen[m] - 1) {
          int s = sId[m];
          if (is_tgt) {
            if (m == 0) emb[(size_t)MID * H_N + j] = nh;
          } else if (s != MID) {
            emb[(size_t)s * H_N + j] = nh;
          }
        }
      }
    }
    __syncthreads();
  }

#pragma unroll
  for (int rr = 0; rr < 7; ++rr) {
    int e = tid + 512 * rr;
    if (e < 16 * H_N) {
      int m = e / H_N, j = e - m * H_N;
      int idx = fidx(m, j);
      stateH[(size_t)(b * 16 + m) * H_N + j] = bf2f(sBh[idx]) + bf2f(sBl[idx]);
      stateC[(size_t)(b * 16 + m) * H_N + j] = creg[rr];
    }
  }
}

// ---------------------------------------------------------------------------
// Fallback (tiny ws): streaming word kernel (round-5 style, unchanged).
// ---------------------------------------------------------------------------
__global__ __launch_bounds__(512, 1) void k_word_s(
    const float* __restrict__ words, const int* __restrict__ lengths,
    const int* __restrict__ order,
    const float* __restrict__ h0w, const float* __restrict__ c0w,
    const u16* __restrict__ wihb_ctx, const u16* __restrict__ whhb_ctx,
    const float* __restrict__ bih_ctx, const float* __restrict__ bhh_ctx,
    const u16* __restrict__ wihb_tgt, const u16* __restrict__ whhb_tgt,
    const float* __restrict__ bih_tgt, const float* __restrict__ bhh_tgt,
    float* __restrict__ emb)
{
  const int tid = threadIdx.x;
  const int b = blockIdx.x;
  const bool is_tgt = (b == 65);
  const u16* wih = is_tgt ? wihb_tgt : wihb_ctx;
  const u16* whh = is_tgt ? whhb_tgt : whhb_ctx;
  const float* bih = is_tgt ? bih_tgt : bih_ctx;
  const float* bhh = is_tgt ? bhh_tgt : bhh_ctx;

  __shared__ __align__(16) u16 sXhi[16 * KP];
  __shared__ __align__(16) u16 sXlo[16 * KP];
  __shared__ __align__(16) u16 sHi[16 * KP];
  __shared__ __align__(16) u16 sLo[16 * KP];
  __shared__ float sG[8 * SGP];
  __shared__ float sB[4 * H_N];
  __shared__ int sLen[16], sId[16];

  for (int e = tid; e < 16 * KP; e += 512) {
    sXhi[e] = 0; sXlo[e] = 0; sHi[e] = 0; sLo[e] = 0;
  }
  if (tid < 16) {
    int slot = b * 16 + tid;
    int s = is_tgt ? MID : order[min(slot, S_N - 1)];
    sId[tid] = s;
    sLen[tid] = lengths[s];
  }
  for (int e = tid; e < 4 * H_N; e += 512) sB[e] = bih[e] + bhh[e];
  __syncthreads();

  float creg[7];
#pragma unroll
  for (int r = 0; r < 7; ++r) {
    int e = tid + 512 * r;
    if (e < 16 * H_N) {
      int m = e / H_N, j = e - m * H_N;
      int s = sId[m];
      float h = h0w[(size_t)s * H_N + j];
      u16 hh = f2bf(h);
      sHi[m * KP + j] = hh;
      sLo[m * KP + j] = f2bf(h - bf2f(hh));
      creg[r] = c0w[(size_t)s * H_N + j];
    }
  }
  __syncthreads();
  int Lmax = 1;
  for (int m = 0; m < 16; ++m) Lmax = max(Lmax, sLen[m]);

  const int lane = tid & 63;
  const int wv = tid >> 6;
  const int quad = lane >> 4;
  const int col = lane & 15;
  const int hpass = quad >> 1;

  const u16* aXh = sXhi + col * KP + quad * 8;
  const u16* aXl = sXlo + col * KP + quad * 8;
  const u16* aHh = sHi  + col * KP + quad * 8;
  const u16* aHl = sLo  + col * KP + quad * 8;

#pragma unroll 1
  for (int t = 0; t < Lmax; ++t) {
    for (int e = tid; e < 16 * H_N; e += 512) {
      int m = e / H_N, k = e - m * H_N;
      float v = words[((size_t)sId[m] * W_N + t) * H_N + k];
      u16 vh = f2bf(v);
      sXhi[m * KP + k] = vh;
      sXlo[m * KP + k] = f2bf(v - bf2f(vh));
    }
    __syncthreads();

    f32x4 acc[7];
#pragma unroll
    for (int i = 0; i < 7; ++i) { f32x4 z4 = {0.f, 0.f, 0.f, 0.f}; acc[i] = z4; }

#pragma unroll
    for (int kcc = 0; kcc < 7; ++kcc) {
      bf16x8 axh = *(const bf16x8*)(aXh + kcc * 32);
      bf16x8 axl = *(const bf16x8*)(aXl + kcc * 32);
      bf16x8 ahh = *(const bf16x8*)(aHh + kcc * 32);
      bf16x8 ahl = *(const bf16x8*)(aHl + kcc * 32);
#pragma unroll
      for (int i = 0; i < 7; ++i) {
        if (wv + 8 * i < 50) {
          bf16x8 bw = *pkptr(wih, wv + 8 * i, kcc, lane);
          bf16x8 bh = *pkptr(whh, wv + 8 * i, kcc, lane);
          acc[i] = __builtin_amdgcn_mfma_f32_16x16x32_bf16(axh, bw, acc[i], 0, 0, 0);
          acc[i] = __builtin_amdgcn_mfma_f32_16x16x32_bf16(axl, bw, acc[i], 0, 0, 0);
          acc[i] = __builtin_amdgcn_mfma_f32_16x16x32_bf16(ahh, bh, acc[i], 0, 0, 0);
          acc[i] = __builtin_amdgcn_mfma_f32_16x16x32_bf16(ahl, bh, acc[i], 0, 0, 0);
        }
      }
    }

#pragma unroll 1
    for (int h = 0; h < 2; ++h) {
      if (hpass == h) {
#pragma unroll
        for (int i = 0; i < 7; ++i) {
          int tt = wv + 8 * i;
          if (tt < 50) {
#pragma unroll
            for (int r = 0; r < 4; ++r)
              sG[((quad & 1) * 4 + r) * SGP + tt * 16 + col] = acc[i][r];
          }
        }
      }
      __syncthreads();
#pragma unroll
      for (int rr = 0; rr < 7; ++rr) {
        int e = tid + 512 * rr;
        if (e < 16 * H_N) {
          int m = e / H_N, j = e - m * H_N;
          if ((m >> 3) == h) {
            const float* gRow = sG + (m - 8 * h) * SGP;
            float ig = gRow[j] + sB[j];
            float fg = gRow[H_N + j] + sB[H_N + j];
            float gg = gRow[2 * H_N + j] + sB[2 * H_N + j];
            float og = gRow[3 * H_N + j] + sB[3 * H_N + j];
            float nc = fsigm(fg) * creg[rr] + fsigm(ig) * ftanh(gg);
            float nh = fsigm(og) * ftanh(nc);
            creg[rr] = nc;
            u16 hh = f2bf(nh);
            sHi[m * KP + j] = hh;
            sLo[m * KP + j] = f2bf(nh - bf2f(hh));
            if (t == sLen[m] - 1) {
              int s = sId[m];
              if (is_tgt) {
                if (m == 0) emb[(size_t)MID * H_N + j] = nh;
              } else if (s != MID) {
                emb[(size_t)s * H_N + j] = nh;
              }
            }
          }
        }
      }
      __syncthreads();
    }
  }
}

// ---------------------------------------------------------------------------
// Kernel 2: gx projections for prev/post via MFMA (packed wih).
// Output layout INTERLEAVED for k_sent: gx[t][j*4 + gate], gate 0..3=i,f,g,o.
// ---------------------------------------------------------------------------
__global__ __launch_bounds__(512) void k_gx(
    const float* __restrict__ emb,
    const u16* __restrict__ wihb_prev, const float* __restrict__ bih_prev, const float* __restrict__ bhh_prev,
    const u16* __restrict__ wihb_post, const float* __restrict__ bih_post, const float* __restrict__ bhh_post,
    float* __restrict__ gxp, float* __restrict__ gxq)
{
  const int tid = threadIdx.x;
  const int b = blockIdx.x;
  const bool post = (b >= 33);
  const int t0 = (post ? b - 33 : b) * 16;
  const u16* wih = post ? wihb_post : wihb_prev;
  const float* bih = post ? bih_post : bih_prev;
  const float* bhh = post ? bhh_post : bhh_prev;
  float* out = post ? gxq : gxp;

  __shared__ __align__(16) u16 sEhi[16 * KP];
  __shared__ __align__(16) u16 sElo[16 * KP];
  for (int e = tid; e < 16 * KP; e += 512) { sEhi[e] = 0; sElo[e] = 0; }
  __syncthreads();
  for (int e = tid; e < 16 * H_N; e += 512) {
    int m = e / H_N, k = e - m * H_N;
    int t = t0 + m;
    if (t <= 512) {
      int src = post ? (1024 - t) : t;
      float v = emb[(size_t)src * H_N + k];
      u16 vh = f2bf(v);
      sEhi[m * KP + k] = vh;
      sElo[m * KP + k] = f2bf(v - bf2f(vh));
    }
  }
  __syncthreads();

  const int lane = tid & 63;
  const int wv = tid >> 6;
  const int quad = lane >> 4;
  const int col = lane & 15;
  const u16* aH = sEhi + col * KP + quad * 8;
  const u16* aL = sElo + col * KP + quad * 8;

#pragma unroll 1
  for (int i = 0; i < 7; ++i) {
    int tt = wv + 8 * i;
    if (tt >= 50) break;
    int gate = tt * 16 + col;
    f32x4 acc = {0.f, 0.f, 0.f, 0.f};
#pragma unroll
    for (int kcc = 0; kcc < 7; ++kcc) {
      bf16x8 Ah = *(const bf16x8*)(aH + kcc * 32);
      bf16x8 Al = *(const bf16x8*)(aL + kcc * 32);
      bf16x8 bw = *pkptr(wih, tt, kcc, lane);
      acc = __builtin_amdgcn_mfma_f32_16x16x32_bf16(Ah, bw, acc, 0, 0, 0);
      acc = __builtin_amdgcn_mfma_f32_16x16x32_bf16(Al, bw, acc, 0, 0, 0);
    }
    float bias = bih[gate] + bhh[gate];
    int gp = gate >= 600 ? 3 : (gate >= 400 ? 2 : (gate >= 200 ? 1 : 0));
    int jg = gate - gp * 200;
#pragma unroll
    for (int r = 0; r < 4; ++r) {
      int t = t0 + quad * 4 + r;
      if (t <= 512) out[(size_t)t * FH_N + jg * 4 + gp] = acc[r] + bias;
    }
  }
}

// ---------------------------------------------------------------------------
// Kernel 3: prev/post sentence LSTMs, 513 serial steps.
// Round-7 structure: 512 threads (8 waves, 2 waves/SIMD -> 256 total regs
// per wave, the r6 lesson). Per wave: 4 asm-AGPR tiles (tt = wv+8*i, i=0..3
// -> tiles 0..31; 112 AGPR) + 2-3 LDS tiles (tt = 32+wv+8*li; 18 tiles,
// 126 KB staged once; builtin MFMA). Budget/wave: A ~124 (112 asm + ~12
// builtin accL), V ~100 -> ~224 of 256, slack 32. Same AGPR coverage as
// round 5 (32 tiles) but 2 waves/SIMD TLP overlaps the 126-ds_read/step
// LDS weight stream with MFMA + elementwise + barriers (round 5 exposed
// them serially at 1 wave/SIMD -> 3900 cyc/step).
// Cluster order verified r5: asm -> sched_barrier -> builtin (natural
// drain) -> sched_barrier + s_nops -> gate stores.
// Gate-interleaved whh packing: each lane's f32x4 acc = (i,f,g,o) of hidden
// unit j = tt*4+quad; hi/lo via B-column trick (cols 0-7 hi, 8-15 lo).
// ---------------------------------------------------------------------------
__global__ __launch_bounds__(512, 1) void k_sent(
    const u16* __restrict__ whhb_prev, const u16* __restrict__ whhb_post,
    const float* __restrict__ h0p, const float* __restrict__ c0p,
    const float* __restrict__ h0q, const float* __restrict__ c0q,
    const float* __restrict__ gxp, const float* __restrict__ gxq,
    float* __restrict__ outp, float* __restrict__ outq)
{
  const int tid = threadIdx.x;
  const bool post = (blockIdx.x != 0);
  const u16* whh = post ? whhb_post : whhb_prev;
  const float* h0 = post ? h0q : h0p;
  const float* c0 = post ? c0q : c0p;
  const float* gx = post ? gxq : gxp;
  float* outv = post ? outq : outp;

  __shared__ __align__(16) u16 sHi[224];
  __shared__ __align__(16) u16 sLo[224];
  __shared__ __align__(16) float sGt[H_N * 8];       // [j][0..3]=hi, [4..7]=lo
  __shared__ __align__(16) u16 sW[18 * 7 * 512];     // weight tiles tt=32..49

  const int lane = tid & 63;
  const int wv = tid >> 6;
  const int quad = lane >> 4;
  const int col = lane & 15;

  // asm-AGPR tiles: tt = wv + 8*i, i=0..3 (covers 0..31, all real)
  bf16x8 afrA[4][7];
#pragma unroll
  for (int i = 0; i < 4; ++i)
#pragma unroll
    for (int kcc = 0; kcc < 7; ++kcc)
      afrA[i][kcc] = *pkptr(whh, wv + 8 * i, kcc, lane);

  // stage tiles 32..49 (126 KB) into LDS once
  {
    const uint4* src = (const uint4*)(whh + 32 * 7 * 512);
    uint4* dst = (uint4*)sW;
    for (int e = tid; e < 18 * 7 * 512 / 8; e += 512) dst[e] = src[e];
  }

  if (tid < 224) { sHi[tid] = 0; sLo[tid] = 0; }
  float c = 0.f, last_h = 0.f;
  if (tid < H_N) {
    float h = h0[tid];
    u16 hh = f2bf(h);
    sHi[tid] = hh;
    sLo[tid] = f2bf(h - bf2f(hh));
    c = c0[tid];
  }
  __syncthreads();

  const u16* hb = ((lane & 8) ? sLo : sHi) + quad * 8;
  const bool wr = ((col & 7) == 0);   // cols 0 (hi) and 8 (lo) write gates
  const int wroff = (col >> 1);       // 0 or 4 floats
  // LDS tiles for this wave: tt = 32 + wv + 8*li, li=0..nL-1
  const int nL = (wv < 2) ? 3 : 2;    // wv>=2, li=2 would be tt>=50 (pad)

  f32x4 gc = {0.f, 0.f, 0.f, 0.f};
  if (tid < H_N) gc = *(const f32x4*)(gx + (size_t)tid * 4);

#pragma unroll 1
  for (int t = 0; t < 513; ++t) {
    bf16x8 bfr[7];
#pragma unroll
    for (int kcc = 0; kcc < 7; ++kcc) bfr[kcc] = *(const bf16x8*)(hb + kcc * 32);

    // prefetch next step's gx; HBM/L2 latency hides under the MFMA phase
    f32x4 gn = {0.f, 0.f, 0.f, 0.f};
    if (t + 1 < 513 && tid < H_N)
      gn = *(const f32x4*)(gx + (size_t)(t + 1) * FH_N + tid * 4);

    // asm AGPR cluster first: zero-C first slice, accumulate after
    f32x4 acc[4];
#pragma unroll
    for (int i = 0; i < 4; ++i) MFMA_A_Z(acc[i], afrA[i][0], bfr[0]);
#pragma unroll
    for (int kcc = 1; kcc < 7; ++kcc)
#pragma unroll
      for (int i = 0; i < 4; ++i)
        MFMA_A(acc[i], afrA[i][kcc], bfr[kcc]);

    __builtin_amdgcn_sched_barrier(0);

    // builtin LDS cluster second: independent work acts as a natural drain
    // for the asm MFMA results (plus explicit nops below).
    f32x4 accL[3];
#pragma unroll
    for (int li = 0; li < 3; ++li) {
      f32x4 z = {0.f, 0.f, 0.f, 0.f};
      accL[li] = z;
      if (li < nL) {                   // wave-uniform
#pragma unroll
        for (int kcc = 0; kcc < 7; ++kcc) {
          bf16x8 aw = *(const bf16x8*)(sW + (size_t)(((wv + 8 * li) * 7 + kcc) * 512) + lane * 8);
          accL[li] = __builtin_amdgcn_mfma_f32_16x16x32_bf16(aw, bfr[kcc], accL[li], 0, 0, 0);
        }
      }
    }

    // explicit hazard drain before any read of asm-written acc
    __builtin_amdgcn_sched_barrier(0);
    asm volatile("s_nop 7\n\ts_nop 7\n\ts_nop 7\n\ts_nop 7\n\ts_nop 7\n\ts_nop 7" ::);
    __builtin_amdgcn_sched_barrier(0);

    if (wr) {
#pragma unroll
      for (int i = 0; i < 4; ++i) {
        int tt = wv + 8 * i;
        *(f32x4*)(sGt + (tt * 4 + quad) * 8 + wroff) = acc[i];
      }
#pragma unroll
      for (int li = 0; li < 3; ++li) {
        if (li < nL) {
          int tt = 32 + wv + 8 * li;
          *(f32x4*)(sGt + (tt * 4 + quad) * 8 + wroff) = accL[li];
        }
      }
    }
    __syncthreads();

    if (tid < H_N) {
      f32x4 ga = *(const f32x4*)(sGt + tid * 8);
      f32x4 gb = *(const f32x4*)(sGt + tid * 8 + 4);
      float ig = ga[0] + gb[0] + gc[0];
      float fg = ga[1] + gb[1] + gc[1];
      float gg = ga[2] + gb[2] + gc[2];
      float og = ga[3] + gb[3] + gc[3];
      float nc = fsigm(fg) * c + fsigm(ig) * ftanh(gg);
      float nh = fsigm(og) * ftanh(nc);
      c = nc;
      last_h = nh;
      u16 hh = f2bf(nh);
      sHi[tid] = hh;
      sLo[tid] = f2bf(nh - bf2f(hh));
    }
    gc = gn;
    __syncthreads();
  }
  if (tid < H_N) outv[tid] = last_h;
}

// ---------------------------------------------------------------------------
// Kernel 4: out = [prev_out ; post_out] @ fc_w^T + fc_b
// ---------------------------------------------------------------------------
__global__ __launch_bounds__(256) void k_fc(
    const float* __restrict__ pout, const float* __restrict__ qout,
    const float* __restrict__ fc_w, const float* __restrict__ fc_b,
    float* __restrict__ out)
{
  const int tid = threadIdx.x;
  if (tid < H_N) {
    float d = fc_b[tid];
    const float* wr = fc_w + (size_t)tid * 2 * H_N;
    for (int k = 0; k < H_N; ++k) d += pout[k] * wr[k];
    for (int k = 0; k < H_N; ++k) d += qout[k] * wr[H_N + k];
    out[tid] = d;
  }
}

extern "C" void kernel_launch(void* const* d_in, const int* in_sizes, int n_in,
                              void* d_out, int out_size, void* d_ws, size_t ws_size,
                              hipStream_t stream) {
  const float* words   = (const float*)d_in[0];
  const int*   lengths = (const int*)d_in[1];
  const float* h0w = (const float*)d_in[2];
  const float* c0w = (const float*)d_in[3];
  const float* h0p = (const float*)d_in[4];
  const float* c0p = (const float*)d_in[5];
  const float* h0q = (const float*)d_in[6];
  const float* c0q = (const float*)d_in[7];
  const float* wih_ctx = (const float*)d_in[8];
  const float* whh_ctx = (const float*)d_in[9];
  const float* bih_ctx = (const float*)d_in[10];
  const float* bhh_ctx = (const float*)d_in[11];
  const float* wih_tgt = (const float*)d_in[12];
  const float* whh_tgt = (const float*)d_in[13];
  const float* bih_tgt = (const float*)d_in[14];
  const float* bhh_tgt = (const float*)d_in[15];
  const float* wih_prev = (const float*)d_in[16];
  const float* whh_prev = (const float*)d_in[17];
  const float* bih_prev = (const float*)d_in[18];
  const float* bhh_prev = (const float*)d_in[19];
  const float* wih_post = (const float*)d_in[20];
  const float* whh_post = (const float*)d_in[21];
  const float* bih_post = (const float*)d_in[22];
  const float* bhh_post = (const float*)d_in[23];
  const float* fc_w = (const float*)d_in[24];
  const float* fc_b = (const float*)d_in[25];
  (void)in_sizes; (void)n_in; (void)out_size;

  const size_t FIXF = 1448600;
  int CH = 0;
  for (int cand = 32; cand >= 1; cand >>= 1) {
    size_t needB = ((size_t)1026 * cand * 800 + FIXF) * 4 + 1056 * 4 + (size_t)8 * PKT * 2 + 256;
    if (ws_size >= needB) { CH = cand; break; }
  }

  float* ws = (float*)d_ws;
  float *gxc, *stateH, *stateC, *emb, *gxp, *gxq, *po, *qo;
  int* order;
  u16* wb;
  if (CH > 0) {
    gxc = ws;
    stateH = gxc + (size_t)1026 * CH * 800;
    stateC = stateH + 211200;
    emb = stateC + 211200;
    gxp = emb + 205000;
    gxq = gxp + 410400;
    po = gxq + 410400;
    qo = po + 200;
    order = (int*)(qo + 200);
    wb = (u16*)(order + 1056);
  } else {
    gxc = nullptr; stateH = nullptr; stateC = nullptr;
    emb = ws;
    gxp = ws + 205000;
    gxq = ws + 615400;
    po = ws + 1025800;
    qo = ws + 1026000;
    order = (int*)(ws + 1026200);
    wb = (u16*)(ws + 1027232);
  }
  u16* wihb_ctx  = wb;
  u16* whhb_ctx  = wb + PKT;
  u16* wihb_tgt  = wb + 2 * PKT;
  u16* whhb_tgt  = wb + 3 * PKT;
  u16* whhb_prev = wb + 4 * PKT;
  u16* whhb_post = wb + 5 * PKT;
  u16* wihb_prev = wb + 6 * PKT;
  u16* wihb_post = wb + 7 * PKT;

  k_w2b<<<(8 * PKT + 255) / 256, 256, 0, stream>>>(
      wih_ctx, whh_ctx, wih_tgt, whh_tgt, whh_prev, whh_post,
      wih_prev, wih_post, wb);
  k_sort<<<1, 1024, 0, stream>>>(lengths, order);

  if (CH > 0) {
    const int TT = (CH + 15) / 16;
    const int NC = (W_N + CH - 1) / CH;
    for (int c = 0; c < NC; ++c) {
      k_xpack<<<1026 * TT, 512, 0, stream>>>(c, CH, words, lengths,
                                             wihb_ctx, bih_ctx, bhh_ctx,
                                             wihb_tgt, bih_tgt, bhh_tgt, gxc);
      k_wrec<<<66, 512, 0, stream>>>(c, CH, lengths, order, h0w, c0w,
                                     whhb_ctx, whhb_tgt, gxc, stateH, stateC, emb);
    }
  } else {
    k_word_s<<<66, 512, 0, stream>>>(words, lengths, order, h0w, c0w,
                                     wihb_ctx, whhb_ctx, bih_ctx, bhh_ctx,
                                     wihb_tgt, whhb_tgt, bih_tgt, bhh_tgt, emb);
  }
  k_gx<<<66, 512, 0, stream>>>(emb, wihb_prev, bih_prev, bhh_prev,
                               wihb_post, bih_post, bhh_post, gxp, gxq);
  k_sent<<<2, 512, 0, stream>>>(whhb_prev, whhb_post, h0p, c0p, h0q, c0q,
                                gxp, gxq, po, qo);
  k_fc<<<1, 256, 0, stream>>>(po, qo, fc_w, fc_b, (float*)d_out);
}